// Round 1
// baseline (1328.151 us; speedup 1.0000x reference)
//
#include <hip/hip_runtime.h>
#include <math.h>

#define DIM   128
#define NA    256
#define NB    64
#define LPROT 2048
#define KSZ   11
#define CW    138   // LDS buffer width: 128 + 2*5 pad
#define RA    62    // input tile rows (32 + 2*15 halo)
#define RB    52    // layer-1 output rows (32 + 2*10)

// ---------------------------------------------------------------- gather xs
__global__ __launch_bounds__(256) void k_gather_fp(const int* __restrict__ fp,
                                                   const float* __restrict__ emb,
                                                   float* __restrict__ xs) {
  int i = blockIdx.x * 256 + threadIdx.x;     // float4 index, total 64*256*32
  int row = i >> 5;
  int c4  = i & 31;
  int f = fp[row];
  reinterpret_cast<float4*>(xs)[i] = reinterpret_cast<const float4*>(emb)[f * 32 + c4];
}

// ------------------------------------------------- GNN: hs = relu(xs@Wg^T+b)
__global__ __launch_bounds__(256) void k_gnn_hs(const float* __restrict__ xs,
                                                const float* __restrict__ Wg,
                                                const float* __restrict__ bg,
                                                float* __restrict__ hs) {
  __shared__ float xrow[8][DIM];
  int base = blockIdx.x * 8;
  for (int idx = threadIdx.x; idx < 8 * DIM; idx += 256)
    xrow[idx >> 7][idx & 127] = xs[(base + (idx >> 7)) * DIM + (idx & 127)];
  __syncthreads();
  int e = threadIdx.x & 127, g = threadIdx.x >> 7;
  float acc[4] = {0.f, 0.f, 0.f, 0.f};
  for (int d = 0; d < DIM; d += 4) {
    float4 w = *(const float4*)&Wg[e * DIM + d];
    #pragma unroll
    for (int j = 0; j < 4; ++j) {
      float4 x = *(const float4*)&xrow[g + 2 * j][d];
      acc[j] = fmaf(x.x, w.x, fmaf(x.y, w.y, fmaf(x.z, w.z, fmaf(x.w, w.w, acc[j]))));
    }
  }
  float b = bg[e];
  #pragma unroll
  for (int j = 0; j < 4; ++j)
    hs[(base + g + 2 * j) * DIM + e] = fmaxf(acc[j] + b, 0.f);
}

// ------------------------------------------------------ GNN: xs += A @ hs
__global__ __launch_bounds__(256) void k_gnn_adj(const float* __restrict__ A,
                                                 const float* __restrict__ hs,
                                                 float* __restrict__ xs) {
  int b  = blockIdx.x >> 4;
  int n0 = (blockIdx.x & 15) * 16;
  __shared__ float As[16][64];
  __shared__ float Hs[64][DIM];
  int e = threadIdx.x & 127, g = threadIdx.x >> 7;
  float acc[8] = {0.f, 0.f, 0.f, 0.f, 0.f, 0.f, 0.f, 0.f};
  for (int k0 = 0; k0 < NA; k0 += 64) {
    __syncthreads();
    for (int i = threadIdx.x; i < 16 * 64; i += 256)
      As[i >> 6][i & 63] = A[(b * NA + n0 + (i >> 6)) * NA + k0 + (i & 63)];
    for (int i = threadIdx.x; i < 64 * DIM; i += 256)
      Hs[i >> 7][i & 127] = hs[(b * NA + k0 + (i >> 7)) * DIM + (i & 127)];
    __syncthreads();
    for (int kk = 0; kk < 64; kk += 4) {
      float h0 = Hs[kk][e], h1 = Hs[kk + 1][e], h2 = Hs[kk + 2][e], h3 = Hs[kk + 3][e];
      #pragma unroll
      for (int j = 0; j < 8; ++j) {
        float4 a = *(const float4*)&As[g + 2 * j][kk];
        acc[j] = fmaf(a.x, h0, fmaf(a.y, h1, fmaf(a.z, h2, fmaf(a.w, h3, acc[j]))));
      }
    }
  }
  #pragma unroll
  for (int j = 0; j < 8; ++j) {
    int idx = (b * NA + n0 + g + 2 * j) * DIM + e;
    xs[idx] += acc[j];
  }
}

// --------------------------------- compound mean + h = relu(compound@Wa^T+ba)
__global__ __launch_bounds__(128) void k_compound_h(const float* __restrict__ xs,
                                                    const float* __restrict__ cmask,
                                                    const float* __restrict__ Wa,
                                                    const float* __restrict__ ba,
                                                    float* __restrict__ compound,
                                                    float* __restrict__ hv) {
  int b = blockIdx.x, e = threadIdx.x;
  __shared__ float comp[DIM];
  float s = 0.f, sc = 0.f;
  for (int n = 0; n < NA; ++n) {
    float m = cmask[b * NA + n];
    s  = fmaf(xs[(b * NA + n) * DIM + e], m, s);
    sc += m;
  }
  float c = s / sc;
  compound[b * DIM + e] = c;
  comp[e] = c;
  __syncthreads();
  float acc = 0.f;
  for (int d = 0; d < DIM; d += 4) {
    float4 w = *(const float4*)&Wa[e * DIM + d];
    float4 x = *(const float4*)&comp[d];
    acc = fmaf(x.x, w.x, fmaf(x.y, w.y, fmaf(x.z, w.z, fmaf(x.w, w.w, acc))));
  }
  hv[b * DIM + e] = fmaxf(acc + ba[e], 0.f);
}

// -------------------------------------------------------- conv layer helper
template <int ROWS, int DSTOFF, bool CHECK>
__device__ inline void conv_layer(const float* src, float* dst,
                                  const float* wk, float bias,
                                  int r0, int rgoff, int tid) {
  for (int s = tid; s < ROWS * 16; s += 256) {
    int rloc = s % ROWS;
    int cs   = (s / ROWS) * 8;
    float acc[8] = {0.f, 0.f, 0.f, 0.f, 0.f, 0.f, 0.f, 0.f};
    for (int ki = 0; ki < KSZ; ++ki) {
      const float* rowp = &src[(rloc + ki) * CW + cs];
      float seg[18];
      #pragma unroll
      for (int j2 = 0; j2 < 9; ++j2) {
        float2 v = *(const float2*)&rowp[2 * j2];
        seg[2 * j2] = v.x; seg[2 * j2 + 1] = v.y;
      }
      #pragma unroll
      for (int kj = 0; kj < KSZ; ++kj) {
        float w = wk[ki * KSZ + kj];
        #pragma unroll
        for (int o = 0; o < 8; ++o) acc[o] = fmaf(seg[kj + o], w, acc[o]);
      }
    }
    bool valid = true;
    if (CHECK) { int rg = r0 + rgoff + rloc; valid = (rg >= 0 && rg < LPROT); }
    #pragma unroll
    for (int o = 0; o < 8; ++o)
      dst[rloc * CW + DSTOFF + cs + o] = valid ? fmaxf(acc[o] + bias, 0.f) : 0.f;
  }
}

// ------------------- fused protein branch: gather+conv3+hs+attention+partials
__global__ __launch_bounds__(256) void k_protein(const int* __restrict__ words,
                                                 const float* __restrict__ emb_word,
                                                 const float* __restrict__ Wc,
                                                 const float* __restrict__ bc,
                                                 const float* __restrict__ Wa,
                                                 const float* __restrict__ ba,
                                                 const float* __restrict__ hvec,
                                                 const float* __restrict__ pmask,
                                                 float* __restrict__ prot_part) {
  int tile = blockIdx.x;          // 0..63 -> rows [tile*32, tile*32+32)
  int b    = blockIdx.y;
  int r0   = tile * 32;
  int tid  = threadIdx.x;

  __shared__ float bufA[RA * CW];
  __shared__ float bufB[RB * CW];
  __shared__ float wk[KSZ * KSZ];
  __shared__ float h_s[DIM];
  __shared__ float red[2 * DIM];
  __shared__ float wpart[32][8];
  __shared__ float w_l[32];

  for (int i = tid; i < RA * CW; i += 256) bufA[i] = 0.f;
  for (int i = tid; i < RB * CW; i += 256) bufB[i] = 0.f;
  if (tid < DIM) h_s[tid] = hvec[b * DIM + tid];
  __syncthreads();

  // stage input rows r0-15 .. r0+46 (gather emb_word) into bufA cols 5..132
  for (int idx = tid; idx < RA * DIM; idx += 256) {
    int i = idx >> 7, c = idx & 127;
    int r = r0 - 15 + i;
    if (r >= 0 && r < LPROT) {
      int w = words[b * LPROT + r];
      bufA[i * CW + 5 + c] = emb_word[w * DIM + c];
    }
  }
  if (tid < KSZ * KSZ) wk[tid] = Wc[tid];
  __syncthreads();

  conv_layer<RB, 5, true>(bufA, bufB, wk, bc[0], r0, -10, tid);   // L1: A->B
  __syncthreads();
  if (tid < KSZ * KSZ) wk[tid] = Wc[KSZ * KSZ + tid];
  __syncthreads();
  conv_layer<42, 5, true>(bufB, bufA, wk, bc[1], r0, -5, tid);    // L2: B->A
  __syncthreads();
  if (tid < KSZ * KSZ) wk[tid] = Wc[2 * KSZ * KSZ + tid];
  __syncthreads();
  conv_layer<32, 0, false>(bufA, bufB, wk, bc[2], r0, 0, tid);    // L3: A->B (no col pad)
  __syncthreads();

  // hs = relu(xs_p @ Wa^T + ba): bufB[32][CW] -> hs_s = bufA[32][128]
  float* hs_s = bufA;
  {
    int e0  = (tid & 31) * 4;
    int rg4 = (tid >> 5) * 4;
    float acc[4][4];
    #pragma unroll
    for (int jr = 0; jr < 4; ++jr)
      #pragma unroll
      for (int k = 0; k < 4; ++k) acc[jr][k] = 0.f;
    for (int d = 0; d < DIM; d += 4) {
      float4 w[4];
      #pragma unroll
      for (int k = 0; k < 4; ++k) w[k] = *(const float4*)&Wa[(e0 + k) * DIM + d];
      #pragma unroll
      for (int jr = 0; jr < 4; ++jr) {
        float2 xa = *(const float2*)&bufB[(rg4 + jr) * CW + d];
        float2 xb = *(const float2*)&bufB[(rg4 + jr) * CW + d + 2];
        #pragma unroll
        for (int k = 0; k < 4; ++k)
          acc[jr][k] = fmaf(xa.x, w[k].x, fmaf(xa.y, w[k].y,
                       fmaf(xb.x, w[k].z, fmaf(xb.y, w[k].w, acc[jr][k]))));
      }
    }
    __syncthreads();   // bufA (conv L2 data) fully consumed above before overwrite
    #pragma unroll
    for (int k = 0; k < 4; ++k) {
      float bv = ba[e0 + k];
      #pragma unroll
      for (int jr = 0; jr < 4; ++jr)
        hs_s[(rg4 + jr) * DIM + e0 + k] = fmaxf(acc[jr][k] + bv, 0.f);
    }
  }
  __syncthreads();

  // weights[l] = tanh(dot(hs[l], h)) * pmask
  {
    int l = tid >> 3, part = tid & 7;
    float p = 0.f;
    int d0 = part * 16;
    #pragma unroll
    for (int dd = 0; dd < 16; ++dd)
      p = fmaf(hs_s[l * DIM + d0 + dd], h_s[d0 + dd], p);
    wpart[l][part] = p;
  }
  __syncthreads();
  if (tid < 32) {
    float s = 0.f;
    #pragma unroll
    for (int k = 0; k < 8; ++k) s += wpart[tid][k];
    w_l[tid] = tanhf(s) * pmask[b * LPROT + r0 + tid];
  }
  __syncthreads();

  // partial protein numerator for this tile
  {
    int e = tid & 127, gq = tid >> 7;
    float pr = 0.f;
    #pragma unroll
    for (int j = 0; j < 16; ++j) {
      int l = gq + 2 * j;
      pr = fmaf(w_l[l], hs_s[l * DIM + e], pr);
    }
    red[gq * DIM + e] = pr;
    __syncthreads();
    if (gq == 0)
      prot_part[(b * 64 + tile) * DIM + e] = red[e] + red[DIM + e];
  }
}

// ------------------------------------------------ head MLP + affinity per b
__global__ __launch_bounds__(256) void k_head(const float* __restrict__ prot_part,
                                              const float* __restrict__ pmask,
                                              const float* __restrict__ compound,
                                              const float* __restrict__ Wo,
                                              const float* __restrict__ bo,
                                              const float* __restrict__ Wi,
                                              const float* __restrict__ bi,
                                              float* __restrict__ out) {
  int b = blockIdx.x, tid = threadIdx.x;
  __shared__ float cat[2 * DIM];
  __shared__ float redl[256];

  float ps = 0.f;
  for (int l = tid; l < LPROT; l += 256) ps += pmask[b * LPROT + l];
  redl[tid] = ps; __syncthreads();
  for (int st = 128; st > 0; st >>= 1) {
    if (tid < st) redl[tid] += redl[tid + st];
    __syncthreads();
  }
  float pden = redl[0];
  __syncthreads();

  if (tid < DIM) {
    cat[tid] = compound[b * DIM + tid];
    float s = 0.f;
    for (int t = 0; t < 64; ++t) s += prot_part[(b * 64 + t) * DIM + tid];
    cat[DIM + tid] = s / pden;
  }
  __syncthreads();

  for (int j = 0; j < 2; ++j) {
    const float* W = Wo + j * 2 * DIM * 2 * DIM + tid * 2 * DIM;
    float acc = 0.f;
    for (int d = 0; d < 2 * DIM; d += 4) {
      float4 c = *(const float4*)&cat[d];
      float4 w = *(const float4*)&W[d];
      acc = fmaf(c.x, w.x, fmaf(c.y, w.y, fmaf(c.z, w.z, fmaf(c.w, w.w, acc))));
    }
    float v = fmaxf(acc + bo[j * 2 * DIM + tid], 0.f);
    __syncthreads();
    cat[tid] = v;
    __syncthreads();
  }

  float p = cat[tid] * Wi[tid];
  redl[tid] = p; __syncthreads();
  for (int st = 128; st > 0; st >>= 1) {
    if (tid < st) redl[tid] += redl[tid + st];
    __syncthreads();
  }
  if (tid == 0) out[1 + b] = redl[0] + bi[0];
}

// ----------------------------------------------------------------- MSE loss
__global__ void k_loss(const float* __restrict__ label, float* __restrict__ out) {
  int t = threadIdx.x;  // 64 threads = 1 wave
  float d = out[1 + t] - label[t];
  float v = d * d;
  #pragma unroll
  for (int s = 32; s > 0; s >>= 1) v += __shfl_down(v, s);
  if (t == 0) out[0] = v * (1.f / 64.f);
}

extern "C" void kernel_launch(void* const* d_in, const int* in_sizes, int n_in,
                              void* d_out, int out_size, void* d_ws, size_t ws_size,
                              hipStream_t stream) {
  const int*   fingerprints = (const int*)d_in[0];
  const float* adjacency    = (const float*)d_in[1];
  const int*   words        = (const int*)d_in[2];
  const float* cmask        = (const float*)d_in[3];
  const float* pmask        = (const float*)d_in[4];
  const float* label        = (const float*)d_in[5];
  const float* emb_fp       = (const float*)d_in[6];
  const float* emb_word     = (const float*)d_in[7];
  const float* Wg           = (const float*)d_in[8];
  const float* bg           = (const float*)d_in[9];
  const float* Wc           = (const float*)d_in[10];
  const float* bc           = (const float*)d_in[11];
  const float* Wa           = (const float*)d_in[12];
  const float* ba           = (const float*)d_in[13];
  const float* Wo           = (const float*)d_in[14];
  const float* bo           = (const float*)d_in[15];
  const float* Wi           = (const float*)d_in[16];
  const float* bi           = (const float*)d_in[17];
  float* out = (float*)d_out;

  float* ws        = (float*)d_ws;
  float* xs        = ws;                        // 64*256*128
  float* hs        = xs + NB * NA * DIM;        // 64*256*128
  float* compound  = hs + NB * NA * DIM;        // 64*128
  float* hv        = compound + NB * DIM;       // 64*128
  float* prot_part = hv + NB * DIM;             // 64*64*128

  k_gather_fp<<<2048, 256, 0, stream>>>(fingerprints, emb_fp, xs);
  for (int i = 0; i < 3; ++i) {
    k_gnn_hs<<<NB * NA / 8, 256, 0, stream>>>(xs, Wg + i * DIM * DIM, bg + i * DIM, hs);
    k_gnn_adj<<<NB * 16, 256, 0, stream>>>(adjacency, hs, xs);
  }
  k_compound_h<<<NB, 128, 0, stream>>>(xs, cmask, Wa, ba, compound, hv);
  k_protein<<<dim3(LPROT / 32, NB), 256, 0, stream>>>(words, emb_word, Wc, bc, Wa, ba,
                                                      hv, pmask, prot_part);
  k_head<<<NB, 256, 0, stream>>>(prot_part, pmask, compound, Wo, bo, Wi, bi, out);
  k_loss<<<1, 64, 0, stream>>>(label, out);
}

// Round 2
// 394.781 us; speedup vs baseline: 3.3643x; 3.3643x over previous
//
#include <hip/hip_runtime.h>
#include <math.h>

#define DIM   128
#define NA    256
#define NB    64
#define LPROT 2048
#define KSZ   11

// protein conv tiling
#define TROWS   64
#define NTILES  (LPROT / TROWS)   // 32
#define RS      152               // bf16 elems per LDS row (304 B, mult of 16B)
#define RSB     304
#define LPAD    8
#define B0_ROWS 106
#define B1_ROWS 96

typedef __attribute__((ext_vector_type(8))) short short8v;
typedef __attribute__((ext_vector_type(4))) short short4v;
typedef __attribute__((ext_vector_type(4))) float float4v;

__device__ inline unsigned short f2bf(float f) {
  union { float f; unsigned u; } v; v.f = f;
  unsigned r = v.u + 0x7FFFu + ((v.u >> 16) & 1u);
  return (unsigned short)(r >> 16);
}
__device__ inline float bf2f(unsigned short s) {
  union { unsigned u; float f; } v; v.u = ((unsigned)s) << 16;
  return v.f;
}

// ---------------------------------------------------------------- gather xs
__global__ __launch_bounds__(256) void k_gather_fp(const int* __restrict__ fp,
                                                   const float* __restrict__ emb,
                                                   float* __restrict__ xs) {
  int i = blockIdx.x * 256 + threadIdx.x;
  int row = i >> 5;
  int c4  = i & 31;
  int f = fp[row];
  reinterpret_cast<float4*>(xs)[i] = reinterpret_cast<const float4*>(emb)[f * 32 + c4];
}

// ------------------------------------------------- GNN: hs = relu(xs@Wg^T+b)
__global__ __launch_bounds__(256) void k_gnn_hs(const float* __restrict__ xs,
                                                const float* __restrict__ Wg,
                                                const float* __restrict__ bg,
                                                float* __restrict__ hs) {
  __shared__ float xrow[8][DIM];
  int base = blockIdx.x * 8;
  for (int idx = threadIdx.x; idx < 8 * DIM; idx += 256)
    xrow[idx >> 7][idx & 127] = xs[(base + (idx >> 7)) * DIM + (idx & 127)];
  __syncthreads();
  int e = threadIdx.x & 127, g = threadIdx.x >> 7;
  float acc[4] = {0.f, 0.f, 0.f, 0.f};
  for (int d = 0; d < DIM; d += 4) {
    float4 w = *(const float4*)&Wg[e * DIM + d];
    #pragma unroll
    for (int j = 0; j < 4; ++j) {
      float4 x = *(const float4*)&xrow[g + 2 * j][d];
      acc[j] = fmaf(x.x, w.x, fmaf(x.y, w.y, fmaf(x.z, w.z, fmaf(x.w, w.w, acc[j]))));
    }
  }
  float b = bg[e];
  #pragma unroll
  for (int j = 0; j < 4; ++j)
    hs[(base + g + 2 * j) * DIM + e] = fmaxf(acc[j] + b, 0.f);
}

// ------------------------------------------------------ GNN: xs += A @ hs
__global__ __launch_bounds__(256) void k_gnn_adj(const float* __restrict__ A,
                                                 const float* __restrict__ hs,
                                                 float* __restrict__ xs) {
  int b  = blockIdx.x >> 4;
  int n0 = (blockIdx.x & 15) * 16;
  __shared__ float As[16][64];
  __shared__ float Hs[64][DIM];
  int e = threadIdx.x & 127, g = threadIdx.x >> 7;
  float acc[8] = {0.f, 0.f, 0.f, 0.f, 0.f, 0.f, 0.f, 0.f};
  for (int k0 = 0; k0 < NA; k0 += 64) {
    __syncthreads();
    for (int i = threadIdx.x; i < 16 * 64; i += 256)
      As[i >> 6][i & 63] = A[(b * NA + n0 + (i >> 6)) * NA + k0 + (i & 63)];
    for (int i = threadIdx.x; i < 64 * DIM; i += 256)
      Hs[i >> 7][i & 127] = hs[(b * NA + k0 + (i >> 7)) * DIM + (i & 127)];
    __syncthreads();
    for (int kk = 0; kk < 64; kk += 4) {
      float h0 = Hs[kk][e], h1 = Hs[kk + 1][e], h2 = Hs[kk + 2][e], h3 = Hs[kk + 3][e];
      #pragma unroll
      for (int j = 0; j < 8; ++j) {
        float4 a = *(const float4*)&As[g + 2 * j][kk];
        acc[j] = fmaf(a.x, h0, fmaf(a.y, h1, fmaf(a.z, h2, fmaf(a.w, h3, acc[j]))));
      }
    }
  }
  #pragma unroll
  for (int j = 0; j < 8; ++j) {
    int idx = (b * NA + n0 + g + 2 * j) * DIM + e;
    xs[idx] += acc[j];
  }
}

// --------------------------------- compound mean + h = relu(compound@Wa^T+ba)
__global__ __launch_bounds__(128) void k_compound_h(const float* __restrict__ xs,
                                                    const float* __restrict__ cmask,
                                                    const float* __restrict__ Wa,
                                                    const float* __restrict__ ba,
                                                    float* __restrict__ compound,
                                                    float* __restrict__ hv) {
  int b = blockIdx.x, e = threadIdx.x;
  __shared__ float comp[DIM];
  float s = 0.f, sc = 0.f;
  for (int n = 0; n < NA; ++n) {
    float m = cmask[b * NA + n];
    s  = fmaf(xs[(b * NA + n) * DIM + e], m, s);
    sc += m;
  }
  float c = s / sc;
  compound[b * DIM + e] = c;
  comp[e] = c;
  __syncthreads();
  float acc = 0.f;
  for (int d = 0; d < DIM; d += 4) {
    float4 w = *(const float4*)&Wa[e * DIM + d];
    float4 x = *(const float4*)&comp[d];
    acc = fmaf(x.x, w.x, fmaf(x.y, w.y, fmaf(x.z, w.z, fmaf(x.w, w.w, acc))));
  }
  hv[b * DIM + e] = fmaxf(acc + ba[e], 0.f);
}

// ------------------- fused protein branch: gather+conv3(MFMA)+hs(MFMA)+attn
__global__ __launch_bounds__(512, 2) void k_protein(const int* __restrict__ words,
                                                    const float* __restrict__ emb_word,
                                                    const float* __restrict__ Wc,
                                                    const float* __restrict__ bc,
                                                    const float* __restrict__ Wa,
                                                    const float* __restrict__ ba,
                                                    const float* __restrict__ hvec,
                                                    const float* __restrict__ pmask,
                                                    float* __restrict__ prot_part) {
  __shared__ __align__(16) unsigned short buf0[B0_ROWS * RS]; // input / L2out / hs
  __shared__ __align__(16) unsigned short buf1[B1_ROWS * RS]; // L1out / L3out
  __shared__ float wpad[KSZ][48];
  __shared__ float h_s[DIM];
  __shared__ float wpart[TROWS][8];
  __shared__ float w_l[TROWS];
  __shared__ float red[4][DIM];

  const int tile = blockIdx.x, b = blockIdx.y;
  const int r0   = tile * TROWS;
  const int tid  = threadIdx.x;
  const int lane = tid & 63, wave = tid >> 6;       // 8 waves
  const int lj   = lane & 15;                       // 0..15
  const int k0   = (lane >> 4) * 8;                 // 0,8,16,24

  // ---- zero LDS buffers (16B stores)
  {
    int4 z = {0, 0, 0, 0};
    int4* p0 = (int4*)buf0;
    int4* p1 = (int4*)buf1;
    for (int i = tid; i < (B0_ROWS * RS) / 8; i += 512) p0[i] = z;
    for (int i = tid; i < (B1_ROWS * RS) / 8; i += 512) p1[i] = z;
  }
  if (tid < DIM) h_s[tid] = hvec[b * DIM + tid];
  __syncthreads();

  // ---- gather input rows r0-15 .. r0+90 as bf16 into buf0
  for (int idx = tid; idx < B0_ROWS * 32; idx += 512) {
    int rloc = idx >> 5, c4 = idx & 31;
    int rg = r0 - 15 + rloc;
    if (rg >= 0 && rg < LPROT) {
      int w = words[b * LPROT + rg];
      float4 v = ((const float4*)(emb_word + (long)w * DIM))[c4];
      short4v s;
      s[0] = (short)f2bf(v.x); s[1] = (short)f2bf(v.y);
      s[2] = (short)f2bf(v.z); s[3] = (short)f2bf(v.w);
      *(short4v*)(&buf0[rloc * RS + LPAD + c4 * 4]) = s;
    }
  }

  const int bbase = 15 + k0 - lj;        // wpad col base (18 + k0 - 3 - j)
  const int cc    = wave;                // each wave owns one 16-col chunk

  // ---- 3 conv layers
  #pragma unroll 1
  for (int lp = 0; lp < 3; ++lp) {
    // stage banded weights into wpad
    __syncthreads();
    for (int i = tid; i < KSZ * 48; i += 512) ((float*)wpad)[i] = 0.f;
    __syncthreads();
    if (tid < KSZ * KSZ) wpad[tid / KSZ][18 + tid % KSZ] = Wc[lp * KSZ * KSZ + tid];
    __syncthreads();

    // build Toeplitz B fragments (bf16) in registers
    short8v bfrag[KSZ];
    #pragma unroll
    for (int ki = 0; ki < KSZ; ++ki) {
      short8v t;
      #pragma unroll
      for (int i = 0; i < 8; ++i) t[i] = (short)f2bf(wpad[ki][bbase + i]);
      bfrag[ki] = t;
    }

    const unsigned short* src = (lp == 1) ? buf1 : buf0;
    unsigned short*       dst = (lp == 1) ? buf0 : buf1;
    const int n_rc   = (lp == 0) ? 6 : (lp == 1) ? 5 : 4;
    const int dstart = r0 - 10 + 5 * lp;   // global row of dst local row 0
    const float bias = bc[lp];
    const char* srcb = (const char*)src;
    const int acolB  = (cc * 16 + k0) * 2;

    for (int rc = 0; rc < n_rc; ++rc) {
      float4v acc = {0.f, 0.f, 0.f, 0.f};
      #pragma unroll
      for (int ki = 0; ki < KSZ; ++ki) {
        int srow = rc * 16 + lj + ki;
        short8v a = *(const short8v*)(srcb + srow * RSB + acolB);
        acc = __builtin_amdgcn_mfma_f32_16x16x32_bf16(a, bfrag[ki], acc, 0, 0, 0);
      }
      int orow = rc * 16 + (lane >> 4) * 4;
      int ocol = cc * 16 + lj;
      #pragma unroll
      for (int jj = 0; jj < 4; ++jj) {
        int grow = dstart + orow + jj;
        float v = fmaxf(acc[jj] + bias, 0.f);
        unsigned short sv = (grow >= 0 && grow < LPROT) ? f2bf(v) : (unsigned short)0;
        dst[(orow + jj) * RS + LPAD + ocol] = sv;
      }
    }
  }
  __syncthreads();

  // ---- hs = relu(X @ Wa^T + ba): X = L3 out (buf1 rows 0..63) -> hs in buf0
  {
    float4v acc[4];
    #pragma unroll
    for (int rc = 0; rc < 4; ++rc) acc[rc] = (float4v){0.f, 0.f, 0.f, 0.f};
    #pragma unroll
    for (int ks = 0; ks < 4; ++ks) {
      const float* wrow = Wa + (cc * 16 + lj) * DIM + ks * 32 + k0;
      float4 wa = *(const float4*)wrow;
      float4 wb = *(const float4*)(wrow + 4);
      short8v bf;
      bf[0] = (short)f2bf(wa.x); bf[1] = (short)f2bf(wa.y);
      bf[2] = (short)f2bf(wa.z); bf[3] = (short)f2bf(wa.w);
      bf[4] = (short)f2bf(wb.x); bf[5] = (short)f2bf(wb.y);
      bf[6] = (short)f2bf(wb.z); bf[7] = (short)f2bf(wb.w);
      #pragma unroll
      for (int rc = 0; rc < 4; ++rc) {
        const char* ap = (const char*)buf1 + (rc * 16 + lj) * RSB + 16 + (ks * 32 + k0) * 2;
        short8v a = *(const short8v*)ap;
        acc[rc] = __builtin_amdgcn_mfma_f32_16x16x32_bf16(a, bf, acc[rc], 0, 0, 0);
      }
    }
    __syncthreads();   // buf0 (L2 data) fully dead; safe to overwrite
    float bav = ba[cc * 16 + lj];
    #pragma unroll
    for (int rc = 0; rc < 4; ++rc) {
      int orow = rc * 16 + (lane >> 4) * 4;
      int ocol = cc * 16 + lj;
      #pragma unroll
      for (int jj = 0; jj < 4; ++jj) {
        float v = fmaxf(acc[rc][jj] + bav, 0.f);
        buf0[(orow + jj) * RS + LPAD + ocol] = f2bf(v);
      }
    }
  }
  __syncthreads();

  // ---- attention weights: w_l = tanh(hs[l]·h) * pmask
  {
    int l = tid >> 3, part = tid & 7, d0 = part * 16;
    float s = 0.f;
    #pragma unroll
    for (int dd = 0; dd < 16; ++dd)
      s = fmaf(bf2f(buf0[l * RS + LPAD + d0 + dd]), h_s[d0 + dd], s);
    wpart[l][part] = s;
  }
  __syncthreads();
  if (tid < TROWS) {
    float s = 0.f;
    #pragma unroll
    for (int p = 0; p < 8; ++p) s += wpart[tid][p];
    w_l[tid] = tanhf(s) * pmask[b * LPROT + r0 + tid];
  }
  __syncthreads();

  // ---- partial protein numerator
  {
    int e = tid & 127, g = tid >> 7;
    float s = 0.f;
    #pragma unroll
    for (int j = 0; j < 16; ++j) {
      int l = g * 16 + j;
      s = fmaf(w_l[l], bf2f(buf0[l * RS + LPAD + e]), s);
    }
    red[g][e] = s;
  }
  __syncthreads();
  if (tid < DIM)
    prot_part[((long)b * NTILES + tile) * DIM + tid] =
        red[0][tid] + red[1][tid] + red[2][tid] + red[3][tid];
}

// ------------------------------------------------ head MLP + affinity per b
__global__ __launch_bounds__(256) void k_head(const float* __restrict__ prot_part,
                                              const float* __restrict__ pmask,
                                              const float* __restrict__ compound,
                                              const float* __restrict__ Wo,
                                              const float* __restrict__ bo,
                                              const float* __restrict__ Wi,
                                              const float* __restrict__ bi,
                                              float* __restrict__ out) {
  int b = blockIdx.x, tid = threadIdx.x;
  __shared__ float cat[2 * DIM];
  __shared__ float redl[256];

  float ps = 0.f;
  for (int l = tid; l < LPROT; l += 256) ps += pmask[b * LPROT + l];
  redl[tid] = ps; __syncthreads();
  for (int st = 128; st > 0; st >>= 1) {
    if (tid < st) redl[tid] += redl[tid + st];
    __syncthreads();
  }
  float pden = redl[0];
  __syncthreads();

  if (tid < DIM) {
    cat[tid] = compound[b * DIM + tid];
    float s = 0.f;
    for (int t = 0; t < NTILES; ++t) s += prot_part[(b * NTILES + t) * DIM + tid];
    cat[DIM + tid] = s / pden;
  }
  __syncthreads();

  for (int j = 0; j < 2; ++j) {
    const float* W = Wo + j * 2 * DIM * 2 * DIM + tid * 2 * DIM;
    float acc = 0.f;
    for (int d = 0; d < 2 * DIM; d += 4) {
      float4 c = *(const float4*)&cat[d];
      float4 w = *(const float4*)&W[d];
      acc = fmaf(c.x, w.x, fmaf(c.y, w.y, fmaf(c.z, w.z, fmaf(c.w, w.w, acc))));
    }
    float v = fmaxf(acc + bo[j * 2 * DIM + tid], 0.f);
    __syncthreads();
    cat[tid] = v;
    __syncthreads();
  }

  float p = cat[tid] * Wi[tid];
  redl[tid] = p; __syncthreads();
  for (int st = 128; st > 0; st >>= 1) {
    if (tid < st) redl[tid] += redl[tid + st];
    __syncthreads();
  }
  if (tid == 0) out[1 + b] = redl[0] + bi[0];
}

// ----------------------------------------------------------------- MSE loss
__global__ void k_loss(const float* __restrict__ label, float* __restrict__ out) {
  int t = threadIdx.x;
  float d = out[1 + t] - label[t];
  float v = d * d;
  #pragma unroll
  for (int s = 32; s > 0; s >>= 1) v += __shfl_down(v, s);
  if (t == 0) out[0] = v * (1.f / 64.f);
}

extern "C" void kernel_launch(void* const* d_in, const int* in_sizes, int n_in,
                              void* d_out, int out_size, void* d_ws, size_t ws_size,
                              hipStream_t stream) {
  const int*   fingerprints = (const int*)d_in[0];
  const float* adjacency    = (const float*)d_in[1];
  const int*   words        = (const int*)d_in[2];
  const float* cmask        = (const float*)d_in[3];
  const float* pmask        = (const float*)d_in[4];
  const float* label        = (const float*)d_in[5];
  const float* emb_fp       = (const float*)d_in[6];
  const float* emb_word     = (const float*)d_in[7];
  const float* Wg           = (const float*)d_in[8];
  const float* bg           = (const float*)d_in[9];
  const float* Wc           = (const float*)d_in[10];
  const float* bc           = (const float*)d_in[11];
  const float* Wa           = (const float*)d_in[12];
  const float* ba           = (const float*)d_in[13];
  const float* Wo           = (const float*)d_in[14];
  const float* bo           = (const float*)d_in[15];
  const float* Wi           = (const float*)d_in[16];
  const float* bi           = (const float*)d_in[17];
  float* out = (float*)d_out;

  float* ws        = (float*)d_ws;
  float* xs        = ws;                        // 64*256*128
  float* hs        = xs + NB * NA * DIM;        // 64*256*128
  float* compound  = hs + NB * NA * DIM;        // 64*128
  float* hv        = compound + NB * DIM;       // 64*128
  float* prot_part = hv + NB * DIM;             // 64*32*128

  k_gather_fp<<<2048, 256, 0, stream>>>(fingerprints, emb_fp, xs);
  for (int i = 0; i < 3; ++i) {
    k_gnn_hs<<<NB * NA / 8, 256, 0, stream>>>(xs, Wg + i * DIM * DIM, bg + i * DIM, hs);
    k_gnn_adj<<<NB * 16, 256, 0, stream>>>(adjacency, hs, xs);
  }
  k_compound_h<<<NB, 128, 0, stream>>>(xs, cmask, Wa, ba, compound, hv);
  k_protein<<<dim3(NTILES, NB), 512, 0, stream>>>(words, emb_word, Wc, bc, Wa, ba,
                                                  hv, pmask, prot_part);
  k_head<<<NB, 256, 0, stream>>>(prot_part, pmask, compound, Wo, bo, Wi, bi, out);
  k_loss<<<1, 64, 0, stream>>>(label, out);
}

// Round 3
// 237.566 us; speedup vs baseline: 5.5907x; 1.6618x over previous
//
#include <hip/hip_runtime.h>
#include <hip/hip_bf16.h>
#include <math.h>

#define DIM   128
#define NA    256
#define NB    64
#define LPROT 2048
#define KSZ   11

// protein conv tiling
#define TROWS   64
#define NTILES  (LPROT / TROWS)   // 32
#define RS      152               // bf16 elems per LDS row (304 B, mult of 16B)
#define RSB     304
#define LPAD    8
#define B0_ROWS 106
#define B1_ROWS 96

// GNN LDS strides (elements)
#define PADK 264    // hsT LDS row stride: 256 + 8
#define PADW 136    // Wg LDS row stride: 128 + 8

typedef __attribute__((ext_vector_type(8))) short short8v;
typedef __attribute__((ext_vector_type(4))) short short4v;
typedef __attribute__((ext_vector_type(4))) float float4v;

__device__ inline unsigned short f2bf(float f) {
  __hip_bfloat16 h = __float2bfloat16(f);
  unsigned short u; __builtin_memcpy(&u, &h, 2); return u;
}
__device__ inline float bf2f(unsigned short s) {
  union { unsigned u; float f; } v; v.u = ((unsigned)s) << 16;
  return v.f;
}

// ---------------------------------------------------------------- gather xs
__global__ __launch_bounds__(256) void k_gather_fp(const int* __restrict__ fp,
                                                   const float* __restrict__ emb,
                                                   float* __restrict__ xs) {
  int i = blockIdx.x * 256 + threadIdx.x;
  int row = i >> 5;
  int c4  = i & 31;
  int f = fp[row];
  reinterpret_cast<float4*>(xs)[i] = reinterpret_cast<const float4*>(emb)[f * 32 + c4];
}

// ---------------------- GNN kernel A: hsT = relu(xs @ Wg^T + bg)^T  (bf16)
// grid: 256 blocks (16384 rows / 64), 256 threads = 4 waves (2x2 wave tile)
__global__ __launch_bounds__(256) void k_gnn_hs2(const float* __restrict__ xs,
                                                 const float* __restrict__ Wg,
                                                 const float* __restrict__ bg,
                                                 unsigned short* __restrict__ hsT) {
  __shared__ unsigned short wgl[128 * PADW];
  const int tid = threadIdx.x, lane = tid & 63, w = tid >> 6;
  const int lj = lane & 15, k0 = (lane >> 4) * 8;

  // stage Wg as bf16 [128][PADW]
  for (int i = tid; i < 128 * 32; i += 256) {
    int row = i >> 5, c4 = (i & 31) * 4;
    float4 v = *(const float4*)&Wg[row * 128 + c4];
    short4v s;
    s[0] = (short)f2bf(v.x); s[1] = (short)f2bf(v.y);
    s[2] = (short)f2bf(v.z); s[3] = (short)f2bf(v.w);
    *(short4v*)&wgl[row * PADW + c4] = s;
  }
  __syncthreads();

  const int blk   = blockIdx.x;
  const int rbase = blk * 64 + (w >> 1) * 32;   // global row in [0,16384)
  const int c0    = (w & 1) * 64;

  // A-fragments: xs rows (fp32 -> bf16)
  short8v afr[4][2];
  #pragma unroll
  for (int ks = 0; ks < 4; ++ks)
    #pragma unroll
    for (int m = 0; m < 2; ++m) {
      const float* p = &xs[(long)(rbase + m * 16 + lj) * DIM + ks * 32 + k0];
      float4 a = *(const float4*)p, b = *(const float4*)(p + 4);
      short8v t;
      t[0] = (short)f2bf(a.x); t[1] = (short)f2bf(a.y);
      t[2] = (short)f2bf(a.z); t[3] = (short)f2bf(a.w);
      t[4] = (short)f2bf(b.x); t[5] = (short)f2bf(b.y);
      t[6] = (short)f2bf(b.z); t[7] = (short)f2bf(b.w);
      afr[ks][m] = t;
    }

  float4v acc[2][4];
  #pragma unroll
  for (int m = 0; m < 2; ++m)
    #pragma unroll
    for (int c = 0; c < 4; ++c) acc[m][c] = (float4v){0.f, 0.f, 0.f, 0.f};

  #pragma unroll
  for (int ks = 0; ks < 4; ++ks)
    #pragma unroll
    for (int c = 0; c < 4; ++c) {
      short8v bf = *(const short8v*)&wgl[(c0 + c * 16 + lj) * PADW + ks * 32 + k0];
      acc[0][c] = __builtin_amdgcn_mfma_f32_16x16x32_bf16(afr[ks][0], bf, acc[0][c], 0, 0, 0);
      acc[1][c] = __builtin_amdgcn_mfma_f32_16x16x32_bf16(afr[ks][1], bf, acc[1][c], 0, 0, 0);
    }

  // epilogue: relu(acc+bg) -> hsT[b][e][n] (bf16), 4 rows packed per store
  const int b = blk >> 2;
  const int nbase = (blk & 3) * 64 + (w >> 1) * 32;
  #pragma unroll
  for (int m = 0; m < 2; ++m)
    #pragma unroll
    for (int c = 0; c < 4; ++c) {
      int e = c0 + c * 16 + lj;
      float bias = bg[e];
      int n0 = nbase + m * 16 + (lane >> 4) * 4;
      short4v s;
      #pragma unroll
      for (int jj = 0; jj < 4; ++jj)
        s[jj] = (short)f2bf(fmaxf(acc[m][c][jj] + bias, 0.f));
      *(short4v*)&hsT[((long)b * DIM + e) * NA + n0] = s;
    }
}

// ---------------------- GNN kernel B: xs += A @ hs   (A fp32->bf16, MFMA)
// grid: 256 blocks (64 batches x 4 row-tiles), 256 threads = 4 waves
__global__ __launch_bounds__(256) void k_gnn_adj2(const float* __restrict__ A,
                                                  const unsigned short* __restrict__ hsT,
                                                  float* __restrict__ xs) {
  __shared__ unsigned short hl[128 * PADK];
  const int tid = threadIdx.x, lane = tid & 63, w = tid >> 6;
  const int lj = lane & 15, k0 = (lane >> 4) * 8;
  const int blk = blockIdx.x;
  const int b = blk >> 2, n0 = (blk & 3) * 64;

  // stage hsT[b] (128 x 256 bf16) into padded LDS
  for (int i = tid; i < 4096; i += 256) {
    int row = i >> 5, c8 = (i & 31) * 8;
    *(short8v*)&hl[row * PADK + c8] =
        *(const short8v*)&hsT[(long)b * (DIM * NA) + row * NA + c8];
  }
  __syncthreads();

  const int r0 = n0 + (w >> 1) * 32;
  const int c0 = (w & 1) * 64;

  float4v acc[2][4];
  #pragma unroll
  for (int m = 0; m < 2; ++m)
    #pragma unroll
    for (int c = 0; c < 4; ++c) acc[m][c] = (float4v){0.f, 0.f, 0.f, 0.f};

  for (int ks = 0; ks < 8; ++ks) {
    short8v af[2];
    #pragma unroll
    for (int m = 0; m < 2; ++m) {
      const float* p = &A[((long)b * NA + r0 + m * 16 + lj) * NA + ks * 32 + k0];
      float4 x = *(const float4*)p, y = *(const float4*)(p + 4);
      short8v t;
      t[0] = (short)f2bf(x.x); t[1] = (short)f2bf(x.y);
      t[2] = (short)f2bf(x.z); t[3] = (short)f2bf(x.w);
      t[4] = (short)f2bf(y.x); t[5] = (short)f2bf(y.y);
      t[6] = (short)f2bf(y.z); t[7] = (short)f2bf(y.w);
      af[m] = t;
    }
    #pragma unroll
    for (int c = 0; c < 4; ++c) {
      short8v bf = *(const short8v*)&hl[(c0 + c * 16 + lj) * PADK + ks * 32 + k0];
      acc[0][c] = __builtin_amdgcn_mfma_f32_16x16x32_bf16(af[0], bf, acc[0][c], 0, 0, 0);
      acc[1][c] = __builtin_amdgcn_mfma_f32_16x16x32_bf16(af[1], bf, acc[1][c], 0, 0, 0);
    }
  }

  #pragma unroll
  for (int m = 0; m < 2; ++m)
    #pragma unroll
    for (int c = 0; c < 4; ++c) {
      int e = c0 + c * 16 + lj;
      int rb = r0 + m * 16 + (lane >> 4) * 4;
      #pragma unroll
      for (int jj = 0; jj < 4; ++jj) {
        long idx = ((long)b * NA + rb + jj) * DIM + e;
        xs[idx] += acc[m][c][jj];
      }
    }
}

// --------------------------------- compound mean + h = relu(compound@Wa^T+ba)
__global__ __launch_bounds__(256) void k_compound_h(const float* __restrict__ xs,
                                                    const float* __restrict__ cmask,
                                                    const float* __restrict__ Wa,
                                                    const float* __restrict__ ba,
                                                    float* __restrict__ compound,
                                                    float* __restrict__ hv) {
  int b = blockIdx.x, tid = threadIdx.x, e = tid & 127, g = tid >> 7;
  __shared__ float red2[2][DIM];
  __shared__ float comp[DIM];
  __shared__ float scs[2];
  float s = 0.f, sc = 0.f;
  for (int n = g * 128; n < (g + 1) * 128; ++n) {
    float m = cmask[b * NA + n];
    s  = fmaf(xs[(b * NA + n) * DIM + e], m, s);
    sc += m;
  }
  red2[g][e] = s;
  if (e == 0) scs[g] = sc;
  __syncthreads();
  if (tid < DIM) {
    float c = (red2[0][tid] + red2[1][tid]) / (scs[0] + scs[1]);
    compound[b * DIM + tid] = c;
    comp[tid] = c;
  }
  __syncthreads();
  if (tid < DIM) {
    float acc = 0.f;
    for (int d = 0; d < DIM; d += 4) {
      float4 w = *(const float4*)&Wa[tid * DIM + d];
      float4 x = *(const float4*)&comp[d];
      acc = fmaf(x.x, w.x, fmaf(x.y, w.y, fmaf(x.z, w.z, fmaf(x.w, w.w, acc))));
    }
    hv[b * DIM + tid] = fmaxf(acc + ba[tid], 0.f);
  }
}

// ------------------- fused protein branch: gather+conv3(MFMA)+hs(MFMA)+attn
__global__ __launch_bounds__(512, 2) void k_protein(const int* __restrict__ words,
                                                    const float* __restrict__ emb_word,
                                                    const float* __restrict__ Wc,
                                                    const float* __restrict__ bc,
                                                    const float* __restrict__ Wa,
                                                    const float* __restrict__ ba,
                                                    const float* __restrict__ hvec,
                                                    const float* __restrict__ pmask,
                                                    float* __restrict__ prot_part) {
  __shared__ __align__(16) unsigned short buf0[B0_ROWS * RS]; // input / L2out / hs
  __shared__ __align__(16) unsigned short buf1[B1_ROWS * RS]; // L1out / L3out
  __shared__ float wpad[KSZ][48];
  __shared__ float h_s[DIM];
  __shared__ float wpart[TROWS][8];
  __shared__ float w_l[TROWS];
  __shared__ float red[4][DIM];

  const int tile = blockIdx.x, b = blockIdx.y;
  const int r0   = tile * TROWS;
  const int tid  = threadIdx.x;
  const int lane = tid & 63, wave = tid >> 6;       // 8 waves
  const int lj   = lane & 15;                       // 0..15
  const int k0   = (lane >> 4) * 8;                 // 0,8,16,24

  // ---- zero LDS buffers (16B stores)
  {
    int4 z = {0, 0, 0, 0};
    int4* p0 = (int4*)buf0;
    int4* p1 = (int4*)buf1;
    for (int i = tid; i < (B0_ROWS * RS) / 8; i += 512) p0[i] = z;
    for (int i = tid; i < (B1_ROWS * RS) / 8; i += 512) p1[i] = z;
  }
  if (tid < DIM) h_s[tid] = hvec[b * DIM + tid];
  __syncthreads();

  // ---- gather input rows r0-15 .. r0+90 as bf16 into buf0
  for (int idx = tid; idx < B0_ROWS * 32; idx += 512) {
    int rloc = idx >> 5, c4 = idx & 31;
    int rg = r0 - 15 + rloc;
    if (rg >= 0 && rg < LPROT) {
      int w = words[b * LPROT + rg];
      float4 v = ((const float4*)(emb_word + (long)w * DIM))[c4];
      short4v s;
      s[0] = (short)f2bf(v.x); s[1] = (short)f2bf(v.y);
      s[2] = (short)f2bf(v.z); s[3] = (short)f2bf(v.w);
      *(short4v*)(&buf0[rloc * RS + LPAD + c4 * 4]) = s;
    }
  }

  const int bbase = 15 + k0 - lj;        // wpad col base (18 + k0 - 3 - j)
  const int cc    = wave;                // each wave owns one 16-col chunk

  // ---- 3 conv layers
  #pragma unroll 1
  for (int lp = 0; lp < 3; ++lp) {
    // stage banded weights into wpad
    __syncthreads();
    for (int i = tid; i < KSZ * 48; i += 512) ((float*)wpad)[i] = 0.f;
    __syncthreads();
    if (tid < KSZ * KSZ) wpad[tid / KSZ][18 + tid % KSZ] = Wc[lp * KSZ * KSZ + tid];
    __syncthreads();

    // build Toeplitz B fragments (bf16) in registers
    short8v bfrag[KSZ];
    #pragma unroll
    for (int ki = 0; ki < KSZ; ++ki) {
      short8v t;
      #pragma unroll
      for (int i = 0; i < 8; ++i) t[i] = (short)f2bf(wpad[ki][bbase + i]);
      bfrag[ki] = t;
    }

    const unsigned short* src = (lp == 1) ? buf1 : buf0;
    unsigned short*       dst = (lp == 1) ? buf0 : buf1;
    const int n_rc   = (lp == 0) ? 6 : (lp == 1) ? 5 : 4;
    const int dstart = r0 - 10 + 5 * lp;   // global row of dst local row 0
    const float bias = bc[lp];
    const char* srcb = (const char*)src;
    const int acolB  = (cc * 16 + k0) * 2;

    for (int rc = 0; rc < n_rc; ++rc) {
      float4v acc = {0.f, 0.f, 0.f, 0.f};
      #pragma unroll
      for (int ki = 0; ki < KSZ; ++ki) {
        int srow = rc * 16 + lj + ki;
        short8v a = *(const short8v*)(srcb + srow * RSB + acolB);
        acc = __builtin_amdgcn_mfma_f32_16x16x32_bf16(a, bfrag[ki], acc, 0, 0, 0);
      }
      int orow = rc * 16 + (lane >> 4) * 4;
      int ocol = cc * 16 + lj;
      #pragma unroll
      for (int jj = 0; jj < 4; ++jj) {
        int grow = dstart + orow + jj;
        float v = fmaxf(acc[jj] + bias, 0.f);
        unsigned short sv = (grow >= 0 && grow < LPROT) ? f2bf(v) : (unsigned short)0;
        dst[(orow + jj) * RS + LPAD + ocol] = sv;
      }
    }
  }
  __syncthreads();

  // ---- hs = relu(X @ Wa^T + ba): X = L3 out (buf1 rows 0..63) -> hs in buf0
  {
    float4v acc[4];
    #pragma unroll
    for (int rc = 0; rc < 4; ++rc) acc[rc] = (float4v){0.f, 0.f, 0.f, 0.f};
    #pragma unroll
    for (int ks = 0; ks < 4; ++ks) {
      const float* wrow = Wa + (cc * 16 + lj) * DIM + ks * 32 + k0;
      float4 wa = *(const float4*)wrow;
      float4 wb = *(const float4*)(wrow + 4);
      short8v bf;
      bf[0] = (short)f2bf(wa.x); bf[1] = (short)f2bf(wa.y);
      bf[2] = (short)f2bf(wa.z); bf[3] = (short)f2bf(wa.w);
      bf[4] = (short)f2bf(wb.x); bf[5] = (short)f2bf(wb.y);
      bf[6] = (short)f2bf(wb.z); bf[7] = (short)f2bf(wb.w);
      #pragma unroll
      for (int rc = 0; rc < 4; ++rc) {
        const char* ap = (const char*)buf1 + (rc * 16 + lj) * RSB + 16 + (ks * 32 + k0) * 2;
        short8v a = *(const short8v*)ap;
        acc[rc] = __builtin_amdgcn_mfma_f32_16x16x32_bf16(a, bf, acc[rc], 0, 0, 0);
      }
    }
    __syncthreads();   // buf0 (L2 data) fully dead; safe to overwrite
    float bav = ba[cc * 16 + lj];
    #pragma unroll
    for (int rc = 0; rc < 4; ++rc) {
      int orow = rc * 16 + (lane >> 4) * 4;
      int ocol = cc * 16 + lj;
      #pragma unroll
      for (int jj = 0; jj < 4; ++jj) {
        float v = fmaxf(acc[rc][jj] + bav, 0.f);
        buf0[(orow + jj) * RS + LPAD + ocol] = f2bf(v);
      }
    }
  }
  __syncthreads();

  // ---- attention weights: w_l = tanh(hs[l]·h) * pmask
  {
    int l = tid >> 3, part = tid & 7, d0 = part * 16;
    float s = 0.f;
    #pragma unroll
    for (int dd = 0; dd < 16; ++dd)
      s = fmaf(bf2f(buf0[l * RS + LPAD + d0 + dd]), h_s[d0 + dd], s);
    wpart[l][part] = s;
  }
  __syncthreads();
  if (tid < TROWS) {
    float s = 0.f;
    #pragma unroll
    for (int p = 0; p < 8; ++p) s += wpart[tid][p];
    w_l[tid] = tanhf(s) * pmask[b * LPROT + r0 + tid];
  }
  __syncthreads();

  // ---- partial protein numerator
  {
    int e = tid & 127, g = tid >> 7;
    float s = 0.f;
    #pragma unroll
    for (int j = 0; j < 16; ++j) {
      int l = g * 16 + j;
      s = fmaf(w_l[l], bf2f(buf0[l * RS + LPAD + e]), s);
    }
    red[g][e] = s;
  }
  __syncthreads();
  if (tid < DIM)
    prot_part[((long)b * NTILES + tile) * DIM + tid] =
        red[0][tid] + red[1][tid] + red[2][tid] + red[3][tid];
}

// ------------------------------------------------ head MLP + affinity per b
__global__ __launch_bounds__(256) void k_head(const float* __restrict__ prot_part,
                                              const float* __restrict__ pmask,
                                              const float* __restrict__ compound,
                                              const float* __restrict__ Wo,
                                              const float* __restrict__ bo,
                                              const float* __restrict__ Wi,
                                              const float* __restrict__ bi,
                                              float* __restrict__ out) {
  int b = blockIdx.x, tid = threadIdx.x;
  __shared__ float cat[2 * DIM];
  __shared__ float redl[256];

  float ps = 0.f;
  for (int l = tid; l < LPROT; l += 256) ps += pmask[b * LPROT + l];
  redl[tid] = ps; __syncthreads();
  for (int st = 128; st > 0; st >>= 1) {
    if (tid < st) redl[tid] += redl[tid + st];
    __syncthreads();
  }
  float pden = redl[0];
  __syncthreads();

  if (tid < DIM) {
    cat[tid] = compound[b * DIM + tid];
    float s = 0.f;
    for (int t = 0; t < NTILES; ++t) s += prot_part[(b * NTILES + t) * DIM + tid];
    cat[DIM + tid] = s / pden;
  }
  __syncthreads();

  for (int j = 0; j < 2; ++j) {
    const float* W = Wo + j * 2 * DIM * 2 * DIM + tid * 2 * DIM;
    float acc = 0.f;
    for (int d = 0; d < 2 * DIM; d += 4) {
      float4 c = *(const float4*)&cat[d];
      float4 w = *(const float4*)&W[d];
      acc = fmaf(c.x, w.x, fmaf(c.y, w.y, fmaf(c.z, w.z, fmaf(c.w, w.w, acc))));
    }
    float v = fmaxf(acc + bo[j * 2 * DIM + tid], 0.f);
    __syncthreads();
    cat[tid] = v;
    __syncthreads();
  }

  float p = cat[tid] * Wi[tid];
  redl[tid] = p; __syncthreads();
  for (int st = 128; st > 0; st >>= 1) {
    if (tid < st) redl[tid] += redl[tid + st];
    __syncthreads();
  }
  if (tid == 0) out[1 + b] = redl[0] + bi[0];
}

// ----------------------------------------------------------------- MSE loss
__global__ void k_loss(const float* __restrict__ label, float* __restrict__ out) {
  int t = threadIdx.x;
  float d = out[1 + t] - label[t];
  float v = d * d;
  #pragma unroll
  for (int s = 32; s > 0; s >>= 1) v += __shfl_down(v, s);
  if (t == 0) out[0] = v * (1.f / 64.f);
}

extern "C" void kernel_launch(void* const* d_in, const int* in_sizes, int n_in,
                              void* d_out, int out_size, void* d_ws, size_t ws_size,
                              hipStream_t stream) {
  const int*   fingerprints = (const int*)d_in[0];
  const float* adjacency    = (const float*)d_in[1];
  const int*   words        = (const int*)d_in[2];
  const float* cmask        = (const float*)d_in[3];
  const float* pmask        = (const float*)d_in[4];
  const float* label        = (const float*)d_in[5];
  const float* emb_fp       = (const float*)d_in[6];
  const float* emb_word     = (const float*)d_in[7];
  const float* Wg           = (const float*)d_in[8];
  const float* bg           = (const float*)d_in[9];
  const float* Wc           = (const float*)d_in[10];
  const float* bc           = (const float*)d_in[11];
  const float* Wa           = (const float*)d_in[12];
  const float* ba           = (const float*)d_in[13];
  const float* Wo           = (const float*)d_in[14];
  const float* bo           = (const float*)d_in[15];
  const float* Wi           = (const float*)d_in[16];
  const float* bi           = (const float*)d_in[17];
  float* out = (float*)d_out;

  float* ws        = (float*)d_ws;
  float* xs        = ws;                               // 64*256*128 f32 (8 MB)
  unsigned short* hsT = (unsigned short*)(xs + NB * NA * DIM);  // 64*128*256 bf16 (4 MB)
  float* compound  = (float*)(hsT + NB * DIM * NA);    // 64*128
  float* hv        = compound + NB * DIM;              // 64*128
  float* prot_part = hv + NB * DIM;                    // 64*32*128

  k_gather_fp<<<2048, 256, 0, stream>>>(fingerprints, emb_fp, xs);
  for (int i = 0; i < 3; ++i) {
    k_gnn_hs2<<<256, 256, 0, stream>>>(xs, Wg + i * DIM * DIM, bg + i * DIM, hsT);
    k_gnn_adj2<<<256, 256, 0, stream>>>(adjacency, hsT, xs);
  }
  k_compound_h<<<NB, 256, 0, stream>>>(xs, cmask, Wa, ba, compound, hv);
  k_protein<<<dim3(NTILES, NB), 512, 0, stream>>>(words, emb_word, Wc, bc, Wa, ba,
                                                  hv, pmask, prot_part);
  k_head<<<NB, 256, 0, stream>>>(prot_part, pmask, compound, Wo, bo, Wi, bi, out);
  k_loss<<<1, 64, 0, stream>>>(label, out);
}

// Round 4
// 219.912 us; speedup vs baseline: 6.0395x; 1.0803x over previous
//
#include <hip/hip_runtime.h>
#include <hip/hip_bf16.h>
#include <math.h>

#define DIM   128
#define NA    256
#define NB    64
#define LPROT 2048
#define KSZ   11

// protein conv tiling (fp8 LDS)
#define TROWS   64
#define NTILES  (LPROT / TROWS)   // 32
#define FRS     152               // fp8 row stride bytes (8 pad + 128 + 16)
#define XRS     136               // bufX bf16 row stride elems (272 B)
#define B0_ROWS 106
#define B1_ROWS 96

// GNN LDS strides (elements)
#define PADK 264    // hsT LDS row stride: 256 + 8
#define PADW 136    // Wg LDS row stride: 128 + 8

typedef __attribute__((ext_vector_type(8))) short short8v;
typedef __attribute__((ext_vector_type(4))) short short4v;
typedef __attribute__((ext_vector_type(4))) float float4v;

__device__ inline unsigned short f2bf(float f) {
  __hip_bfloat16 h = __float2bfloat16(f);
  unsigned short u; __builtin_memcpy(&u, &h, 2); return u;
}
__device__ inline float bf2f(unsigned short s) {
  union { unsigned u; float f; } v; v.u = ((unsigned)s) << 16;
  return v.f;
}

// ---------------------- GNN kernel A: hsT = relu(xs @ Wg^T + bg)^T  (bf16)
// GATHER variant also materializes xs = emb_fp[fingerprints] (layer 0).
template <bool GATHER>
__global__ __launch_bounds__(256) void k_gnn_hs2(const float* __restrict__ xs_in,
                                                 const float* __restrict__ Wg,
                                                 const float* __restrict__ bg,
                                                 unsigned short* __restrict__ hsT,
                                                 const int* __restrict__ fp,
                                                 const float* __restrict__ emb,
                                                 float* __restrict__ xs_out) {
  __shared__ unsigned short wgl[128 * PADW];
  const int tid = threadIdx.x, lane = tid & 63, w = tid >> 6;
  const int lj = lane & 15, k0 = (lane >> 4) * 8;

  // stage Wg as bf16 [128][PADW]
  for (int i = tid; i < 128 * 32; i += 256) {
    int row = i >> 5, c4 = (i & 31) * 4;
    float4 v = *(const float4*)&Wg[row * 128 + c4];
    short4v s;
    s[0] = (short)f2bf(v.x); s[1] = (short)f2bf(v.y);
    s[2] = (short)f2bf(v.z); s[3] = (short)f2bf(v.w);
    *(short4v*)&wgl[row * PADW + c4] = s;
  }
  __syncthreads();

  const int blk   = blockIdx.x;
  const int rbase = blk * 64 + (w >> 1) * 32;   // global row in [0,16384)
  const int c0    = (w & 1) * 64;

  int frow[2];
  if (GATHER) {
    frow[0] = fp[rbase + lj];
    frow[1] = fp[rbase + 16 + lj];
  }

  // A-fragments: xs rows (fp32 -> bf16)
  short8v afr[4][2];
  #pragma unroll
  for (int ks = 0; ks < 4; ++ks)
    #pragma unroll
    for (int m = 0; m < 2; ++m) {
      int grow = rbase + m * 16 + lj;
      const float* p = GATHER ? &emb[(long)frow[m] * DIM + ks * 32 + k0]
                              : &xs_in[(long)grow * DIM + ks * 32 + k0];
      float4 a = *(const float4*)p, b = *(const float4*)(p + 4);
      if (GATHER && !(w & 1)) {
        *(float4*)&xs_out[(long)grow * DIM + ks * 32 + k0] = a;
        *(float4*)&xs_out[(long)grow * DIM + ks * 32 + k0 + 4] = b;
      }
      short8v t;
      t[0] = (short)f2bf(a.x); t[1] = (short)f2bf(a.y);
      t[2] = (short)f2bf(a.z); t[3] = (short)f2bf(a.w);
      t[4] = (short)f2bf(b.x); t[5] = (short)f2bf(b.y);
      t[6] = (short)f2bf(b.z); t[7] = (short)f2bf(b.w);
      afr[ks][m] = t;
    }

  float4v acc[2][4];
  #pragma unroll
  for (int m = 0; m < 2; ++m)
    #pragma unroll
    for (int c = 0; c < 4; ++c) acc[m][c] = (float4v){0.f, 0.f, 0.f, 0.f};

  #pragma unroll
  for (int ks = 0; ks < 4; ++ks)
    #pragma unroll
    for (int c = 0; c < 4; ++c) {
      short8v bf = *(const short8v*)&wgl[(c0 + c * 16 + lj) * PADW + ks * 32 + k0];
      acc[0][c] = __builtin_amdgcn_mfma_f32_16x16x32_bf16(afr[ks][0], bf, acc[0][c], 0, 0, 0);
      acc[1][c] = __builtin_amdgcn_mfma_f32_16x16x32_bf16(afr[ks][1], bf, acc[1][c], 0, 0, 0);
    }

  // epilogue: relu(acc+bg) -> hsT[b][e][n] (bf16)
  const int b = blk >> 2;
  const int nbase = (blk & 3) * 64 + (w >> 1) * 32;
  #pragma unroll
  for (int m = 0; m < 2; ++m)
    #pragma unroll
    for (int c = 0; c < 4; ++c) {
      int e = c0 + c * 16 + lj;
      float bias = bg[e];
      int n0 = nbase + m * 16 + (lane >> 4) * 4;
      short4v s;
      #pragma unroll
      for (int jj = 0; jj < 4; ++jj)
        s[jj] = (short)f2bf(fmaxf(acc[m][c][jj] + bias, 0.f));
      *(short4v*)&hsT[((long)b * DIM + e) * NA + n0] = s;
    }
}

// ---------------------- GNN kernel B: xs += A @ hs   (A fp32->bf16, MFMA)
__global__ __launch_bounds__(256) void k_gnn_adj2(const float* __restrict__ A,
                                                  const unsigned short* __restrict__ hsT,
                                                  float* __restrict__ xs) {
  __shared__ unsigned short hl[128 * PADK];
  const int tid = threadIdx.x, lane = tid & 63, w = tid >> 6;
  const int lj = lane & 15, k0 = (lane >> 4) * 8;
  const int blk = blockIdx.x;
  const int b = blk >> 2, n0 = (blk & 3) * 64;

  for (int i = tid; i < 4096; i += 256) {
    int row = i >> 5, c8 = (i & 31) * 8;
    *(short8v*)&hl[row * PADK + c8] =
        *(const short8v*)&hsT[(long)b * (DIM * NA) + row * NA + c8];
  }
  __syncthreads();

  const int r0 = n0 + (w >> 1) * 32;
  const int c0 = (w & 1) * 64;

  float4v acc[2][4];
  #pragma unroll
  for (int m = 0; m < 2; ++m)
    #pragma unroll
    for (int c = 0; c < 4; ++c) acc[m][c] = (float4v){0.f, 0.f, 0.f, 0.f};

  for (int ks = 0; ks < 8; ++ks) {
    short8v af[2];
    #pragma unroll
    for (int m = 0; m < 2; ++m) {
      const float* p = &A[((long)b * NA + r0 + m * 16 + lj) * NA + ks * 32 + k0];
      float4 x = *(const float4*)p, y = *(const float4*)(p + 4);
      short8v t;
      t[0] = (short)f2bf(x.x); t[1] = (short)f2bf(x.y);
      t[2] = (short)f2bf(x.z); t[3] = (short)f2bf(x.w);
      t[4] = (short)f2bf(y.x); t[5] = (short)f2bf(y.y);
      t[6] = (short)f2bf(y.z); t[7] = (short)f2bf(y.w);
      af[m] = t;
    }
    #pragma unroll
    for (int c = 0; c < 4; ++c) {
      short8v bf = *(const short8v*)&hl[(c0 + c * 16 + lj) * PADK + ks * 32 + k0];
      acc[0][c] = __builtin_amdgcn_mfma_f32_16x16x32_bf16(af[0], bf, acc[0][c], 0, 0, 0);
      acc[1][c] = __builtin_amdgcn_mfma_f32_16x16x32_bf16(af[1], bf, acc[1][c], 0, 0, 0);
    }
  }

  #pragma unroll
  for (int m = 0; m < 2; ++m)
    #pragma unroll
    for (int c = 0; c < 4; ++c) {
      int e = c0 + c * 16 + lj;
      int rb = r0 + m * 16 + (lane >> 4) * 4;
      #pragma unroll
      for (int jj = 0; jj < 4; ++jj) {
        long idx = ((long)b * NA + rb + jj) * DIM + e;
        xs[idx] += acc[m][c][jj];
      }
    }
}

// --------------------------------- compound mean + h = relu(compound@Wa^T+ba)
__global__ __launch_bounds__(256) void k_compound_h(const float* __restrict__ xs,
                                                    const float* __restrict__ cmask,
                                                    const float* __restrict__ Wa,
                                                    const float* __restrict__ ba,
                                                    float* __restrict__ compound,
                                                    float* __restrict__ hv) {
  int b = blockIdx.x, tid = threadIdx.x, e = tid & 127, g = tid >> 7;
  __shared__ float red2[2][DIM];
  __shared__ float comp[DIM];
  __shared__ float scs[2];
  float s = 0.f, sc = 0.f;
  for (int n = g * 128; n < (g + 1) * 128; ++n) {
    float m = cmask[b * NA + n];
    s  = fmaf(xs[(b * NA + n) * DIM + e], m, s);
    sc += m;
  }
  red2[g][e] = s;
  if (e == 0) scs[g] = sc;
  __syncthreads();
  if (tid < DIM) {
    float c = (red2[0][tid] + red2[1][tid]) / (scs[0] + scs[1]);
    compound[b * DIM + tid] = c;
    comp[tid] = c;
  }
  __syncthreads();
  if (tid < DIM) {
    float acc = 0.f;
    for (int d = 0; d < DIM; d += 4) {
      float4 w = *(const float4*)&Wa[tid * DIM + d];
      float4 x = *(const float4*)&comp[d];
      acc = fmaf(x.x, w.x, fmaf(x.y, w.y, fmaf(x.z, w.z, fmaf(x.w, w.w, acc))));
    }
    hv[b * DIM + tid] = fmaxf(acc + ba[tid], 0.f);
  }
}

// ------------------------- fp8 conv phase helper (Toeplitz MFMA) ------------
template <int N_RC, bool ROWCHK, bool BF16OUT>
__device__ inline void conv_fp8(const char* __restrict__ src, char* __restrict__ dst,
                                unsigned short* __restrict__ dstX,
                                const long* bfr, float bias, int dstart,
                                int lane, int cc) {
  const int lj = lane & 15, k0 = (lane >> 4) * 8;
  const int acol = 8 + cc * 16 + k0;
  for (int rc = 0; rc < N_RC; ++rc) {
    float4v acc = {0.f, 0.f, 0.f, 0.f};
    #pragma unroll
    for (int ki = 0; ki < KSZ; ++ki) {
      int srow = rc * 16 + lj + ki;
      long a = *(const long*)(src + srow * FRS + acol);
      acc = __builtin_amdgcn_mfma_f32_16x16x32_fp8_fp8(a, bfr[ki], acc, 0, 0, 0);
    }
    int orow = rc * 16 + (lane >> 4) * 4;
    int ocol = cc * 16 + lj;
    #pragma unroll
    for (int jj = 0; jj < 4; ++jj) {
      float v = fmaxf(acc[jj] + bias, 0.f);
      if constexpr (BF16OUT) {
        dstX[(orow + jj) * XRS + ocol] = f2bf(v);
      } else {
        char sv = 0;
        if (!ROWCHK || (unsigned)(dstart + orow + jj) < LPROT) {
          int p = __builtin_amdgcn_cvt_pk_fp8_f32(v, 0.f, 0, false);
          sv = (char)p;
        }
        dst[(orow + jj) * FRS + 8 + ocol] = sv;
      }
    }
  }
}

// ------------------- fused protein branch: gather+conv3(fp8 MFMA)+hs+attn
__global__ __launch_bounds__(512, 6) void k_protein(const int* __restrict__ words,
                                                    const float* __restrict__ emb_word,
                                                    const float* __restrict__ Wc,
                                                    const float* __restrict__ bc,
                                                    const float* __restrict__ Wa,
                                                    const float* __restrict__ ba,
                                                    const float* __restrict__ hvec,
                                                    const float* __restrict__ pmask,
                                                    float* __restrict__ prot_part) {
  __shared__ __align__(16) char pool[50752];
  char* buf0 = pool;                                     // fp8, 106x152 (16128)
  char* buf1 = pool + 16128;                             // fp8, 96x152 (14592)
  unsigned short* bufX = (unsigned short*)(pool + 30720);// bf16 64x136 (17408)
  float* wpad = (float*)(pool + 48128);                  // 11x48 f32 (2112)
  float* h_s  = (float*)(pool + 50240);                  // 128 f32 (512)
  // overlays in buf1 region (dead after conv L2):
  float* wpart = (float*)(pool + 16128);                 // 64x8
  float* w_l   = (float*)(pool + 16128 + 2048);          // 64
  float* red   = (float*)(pool + 16128 + 2304);          // 4x128

  const int tile = blockIdx.x, b = blockIdx.y;
  const int r0   = tile * TROWS;
  const int tid  = threadIdx.x;
  const int lane = tid & 63, wave = tid >> 6;       // 8 waves
  const int lj   = lane & 15;
  const int k0   = (lane >> 4) * 8;
  const int cc   = wave;                            // 16-col chunk per wave

  // ---- zero fp8 buffers
  {
    int4 z = {0, 0, 0, 0};
    int4* p0 = (int4*)pool;
    for (int i = tid; i < 30720 / 16; i += 512) p0[i] = z;
  }
  if (tid < DIM) h_s[tid] = hvec[b * DIM + tid];
  __syncthreads();

  // ---- gather input rows r0-15 .. r0+90 as fp8 into buf0
  for (int idx = tid; idx < B0_ROWS * 32; idx += 512) {
    int rloc = idx >> 5, c4 = idx & 31;
    int rg = r0 - 15 + rloc;
    if (rg >= 0 && rg < LPROT) {
      int w = words[b * LPROT + rg];
      float4 v = ((const float4*)(emb_word + (long)w * DIM))[c4];
      int p = __builtin_amdgcn_cvt_pk_fp8_f32(v.x, v.y, 0, false);
      p = __builtin_amdgcn_cvt_pk_fp8_f32(v.z, v.w, p, true);
      *(int*)(buf0 + rloc * FRS + 8 + c4 * 4) = p;
    }
  }

  const int bbase = 15 + k0 - lj;        // wpad col base

  // ---- 3 conv layers (fp8 Toeplitz MFMA)
  #pragma unroll 1
  for (int lp = 0; lp < 3; ++lp) {
    __syncthreads();
    for (int i = tid; i < KSZ * 48; i += 512) wpad[i] = 0.f;
    __syncthreads();
    if (tid < KSZ * KSZ) wpad[(tid / KSZ) * 48 + 18 + tid % KSZ] = Wc[lp * KSZ * KSZ + tid];
    __syncthreads();

    long bfr[KSZ];
    #pragma unroll
    for (int ki = 0; ki < KSZ; ++ki) {
      const float* wr = wpad + ki * 48 + bbase;
      int lo = __builtin_amdgcn_cvt_pk_fp8_f32(wr[0], wr[1], 0, false);
      lo = __builtin_amdgcn_cvt_pk_fp8_f32(wr[2], wr[3], lo, true);
      int hi = __builtin_amdgcn_cvt_pk_fp8_f32(wr[4], wr[5], 0, false);
      hi = __builtin_amdgcn_cvt_pk_fp8_f32(wr[6], wr[7], hi, true);
      bfr[ki] = ((long)hi << 32) | (unsigned)lo;
    }
    float bias = bc[lp];

    if (lp == 0)
      conv_fp8<6, true, false>(buf0, buf1, nullptr, bfr, bias, r0 - 10, lane, cc);
    else if (lp == 1)
      conv_fp8<5, true, false>(buf1, buf0, nullptr, bfr, bias, r0 - 5, lane, cc);
    else
      conv_fp8<4, false, true>(buf0, nullptr, bufX, bfr, bias, r0, lane, cc);
  }
  __syncthreads();

  // ---- hs = relu(X @ Wa^T + ba): X = bufX (bf16), output written in place
  {
    const char* xb = (const char*)bufX;
    float4v acc[4];
    #pragma unroll
    for (int rc = 0; rc < 4; ++rc) acc[rc] = (float4v){0.f, 0.f, 0.f, 0.f};
    #pragma unroll
    for (int ks = 0; ks < 4; ++ks) {
      const float* wrow = Wa + (cc * 16 + lj) * DIM + ks * 32 + k0;
      float4 wa = *(const float4*)wrow;
      float4 wb = *(const float4*)(wrow + 4);
      short8v bf;
      bf[0] = (short)f2bf(wa.x); bf[1] = (short)f2bf(wa.y);
      bf[2] = (short)f2bf(wa.z); bf[3] = (short)f2bf(wa.w);
      bf[4] = (short)f2bf(wb.x); bf[5] = (short)f2bf(wb.y);
      bf[6] = (short)f2bf(wb.z); bf[7] = (short)f2bf(wb.w);
      #pragma unroll
      for (int rc = 0; rc < 4; ++rc) {
        short8v a = *(const short8v*)(xb + (rc * 16 + lj) * (XRS * 2) + (ks * 32 + k0) * 2);
        acc[rc] = __builtin_amdgcn_mfma_f32_16x16x32_bf16(a, bf, acc[rc], 0, 0, 0);
      }
    }
    __syncthreads();   // all X reads complete before in-place overwrite
    float bav = ba[cc * 16 + lj];
    #pragma unroll
    for (int rc = 0; rc < 4; ++rc) {
      int orow = rc * 16 + (lane >> 4) * 4;
      int ocol = cc * 16 + lj;
      #pragma unroll
      for (int jj = 0; jj < 4; ++jj) {
        float v = fmaxf(acc[rc][jj] + bav, 0.f);
        bufX[(orow + jj) * XRS + ocol] = f2bf(v);
      }
    }
  }
  __syncthreads();

  // ---- attention weights: w_l = tanh(hs[l]·h) * pmask
  {
    int l = tid >> 3, part = tid & 7, d0 = part * 16;
    float s = 0.f;
    #pragma unroll
    for (int dd = 0; dd < 16; ++dd)
      s = fmaf(bf2f(bufX[l * XRS + d0 + dd]), h_s[d0 + dd], s);
    wpart[l * 8 + part] = s;
  }
  __syncthreads();
  if (tid < TROWS) {
    float s = 0.f;
    #pragma unroll
    for (int p = 0; p < 8; ++p) s += wpart[tid * 8 + p];
    w_l[tid] = tanhf(s) * pmask[b * LPROT + r0 + tid];
  }
  __syncthreads();

  // ---- partial protein numerator
  {
    int e = tid & 127, g = tid >> 7;
    float s = 0.f;
    #pragma unroll
    for (int j = 0; j < 16; ++j) {
      int l = g * 16 + j;
      s = fmaf(w_l[l], bf2f(bufX[l * XRS + e]), s);
    }
    red[g * DIM + e] = s;
  }
  __syncthreads();
  if (tid < DIM)
    prot_part[((long)b * NTILES + tile) * DIM + tid] =
        red[tid] + red[DIM + tid] + red[2 * DIM + tid] + red[3 * DIM + tid];
}

// ------------------------------------------------ head MLP + affinity per b
__global__ __launch_bounds__(256) void k_head(const float* __restrict__ prot_part,
                                              const float* __restrict__ pmask,
                                              const float* __restrict__ compound,
                                              const float* __restrict__ Wo,
                                              const float* __restrict__ bo,
                                              const float* __restrict__ Wi,
                                              const float* __restrict__ bi,
                                              float* __restrict__ out) {
  int b = blockIdx.x, tid = threadIdx.x;
  __shared__ float cat[2 * DIM];
  __shared__ float redl[256];

  float ps = 0.f;
  for (int l = tid; l < LPROT; l += 256) ps += pmask[b * LPROT + l];
  redl[tid] = ps; __syncthreads();
  for (int st = 128; st > 0; st >>= 1) {
    if (tid < st) redl[tid] += redl[tid + st];
    __syncthreads();
  }
  float pden = redl[0];
  __syncthreads();

  if (tid < DIM) {
    cat[tid] = compound[b * DIM + tid];
    float s = 0.f;
    for (int t = 0; t < NTILES; ++t) s += prot_part[(b * NTILES + t) * DIM + tid];
    cat[DIM + tid] = s / pden;
  }
  __syncthreads();

  for (int j = 0; j < 2; ++j) {
    const float* W = Wo + j * 2 * DIM * 2 * DIM + tid * 2 * DIM;
    float acc = 0.f;
    for (int d = 0; d < 2 * DIM; d += 4) {
      float4 c = *(const float4*)&cat[d];
      float4 w = *(const float4*)&W[d];
      acc = fmaf(c.x, w.x, fmaf(c.y, w.y, fmaf(c.z, w.z, fmaf(c.w, w.w, acc))));
    }
    float v = fmaxf(acc + bo[j * 2 * DIM + tid], 0.f);
    __syncthreads();
    cat[tid] = v;
    __syncthreads();
  }

  float p = cat[tid] * Wi[tid];
  redl[tid] = p; __syncthreads();
  for (int st = 128; st > 0; st >>= 1) {
    if (tid < st) redl[tid] += redl[tid + st];
    __syncthreads();
  }
  if (tid == 0) out[1 + b] = redl[0] + bi[0];
}

// ----------------------------------------------------------------- MSE loss
__global__ void k_loss(const float* __restrict__ label, float* __restrict__ out) {
  int t = threadIdx.x;
  float d = out[1 + t] - label[t];
  float v = d * d;
  #pragma unroll
  for (int s = 32; s > 0; s >>= 1) v += __shfl_down(v, s);
  if (t == 0) out[0] = v * (1.f / 64.f);
}

extern "C" void kernel_launch(void* const* d_in, const int* in_sizes, int n_in,
                              void* d_out, int out_size, void* d_ws, size_t ws_size,
                              hipStream_t stream) {
  const int*   fingerprints = (const int*)d_in[0];
  const float* adjacency    = (const float*)d_in[1];
  const int*   words        = (const int*)d_in[2];
  const float* cmask        = (const float*)d_in[3];
  const float* pmask        = (const float*)d_in[4];
  const float* label        = (const float*)d_in[5];
  const float* emb_fp       = (const float*)d_in[6];
  const float* emb_word     = (const float*)d_in[7];
  const float* Wg           = (const float*)d_in[8];
  const float* bg           = (const float*)d_in[9];
  const float* Wc           = (const float*)d_in[10];
  const float* bc           = (const float*)d_in[11];
  const float* Wa           = (const float*)d_in[12];
  const float* ba           = (const float*)d_in[13];
  const float* Wo           = (const float*)d_in[14];
  const float* bo           = (const float*)d_in[15];
  const float* Wi           = (const float*)d_in[16];
  const float* bi           = (const float*)d_in[17];
  float* out = (float*)d_out;

  float* ws        = (float*)d_ws;
  float* xs        = ws;                               // 64*256*128 f32 (8 MB)
  unsigned short* hsT = (unsigned short*)(xs + NB * NA * DIM);  // bf16 (4 MB)
  float* compound  = (float*)(hsT + NB * DIM * NA);    // 64*128
  float* hv        = compound + NB * DIM;              // 64*128
  float* prot_part = hv + NB * DIM;                    // 64*32*128

  k_gnn_hs2<true><<<256, 256, 0, stream>>>(nullptr, Wg, bg, hsT,
                                           fingerprints, emb_fp, xs);
  k_gnn_adj2<<<256, 256, 0, stream>>>(adjacency, hsT, xs);
  for (int i = 1; i < 3; ++i) {
    k_gnn_hs2<false><<<256, 256, 0, stream>>>(xs, Wg + i * DIM * DIM, bg + i * DIM,
                                              hsT, nullptr, nullptr, nullptr);
    k_gnn_adj2<<<256, 256, 0, stream>>>(adjacency, hsT, xs);
  }
  k_compound_h<<<NB, 256, 0, stream>>>(xs, cmask, Wa, ba, compound, hv);
  k_protein<<<dim3(NTILES, NB), 512, 0, stream>>>(words, emb_word, Wc, bc, Wa, ba,
                                                  hv, pmask, prot_part);
  k_head<<<NB, 256, 0, stream>>>(prot_part, pmask, compound, Wo, bo, Wi, bi, out);
  k_loss<<<1, 64, 0, stream>>>(label, out);
}

// Round 5
// 156.500 us; speedup vs baseline: 8.4866x; 1.4052x over previous
//
#include <hip/hip_runtime.h>
#include <hip/hip_bf16.h>
#include <math.h>

#define DIM   128
#define NA    256
#define NB    64
#define LPROT 2048
#define KSZ   11

// protein conv tiling (fp8 LDS)
#define TROWS   64
#define NTILES  (LPROT / TROWS)   // 32
#define FRS     152               // fp8 row stride bytes (8 pad + 128 + 16)
#define XRS     136               // bufX bf16 row stride elems (272 B)
#define B0_ROWS 106
#define B1_ROWS 96

typedef __attribute__((ext_vector_type(8))) short short8v;
typedef __attribute__((ext_vector_type(4))) short short4v;
typedef __attribute__((ext_vector_type(4))) float float4v;

__device__ inline unsigned short f2bf(float f) {
  __hip_bfloat16 h = __float2bfloat16(f);
  unsigned short u; __builtin_memcpy(&u, &h, 2); return u;
}
__device__ inline float bf2f(unsigned short s) {
  union { unsigned u; float f; } v; v.u = ((unsigned)s) << 16;
  return v.f;
}

// -------------------- fused GNN: gather + 3x(hs,adj) + compound + hv --------
// One block per batch. xs kept in f32 registers (MFMA C-layout).
// LDS: region0 (64KB) = xs_lds bf16[256][128] / hsT_lds bf16[128][256] (overlaid)
//      wg (32KB) = Wg bf16[128][128]. All XOR-swizzled: byte ^= (row&7)<<4.
#define GSTR 256
#define HSTR 512
#define WSTR 256
__device__ inline int xsa(int n, int cb) { return (n * GSTR + cb) ^ ((n & 7) << 4); }
__device__ inline int hta(int e, int nb) { return (e * HSTR + nb) ^ ((e & 7) << 4); }
__device__ inline int wga(int e, int cb) { return (e * WSTR + cb) ^ ((e & 7) << 4); }

__global__ __launch_bounds__(512, 2) void k_gnn(const int* __restrict__ fp,
                                                const float* __restrict__ emb,
                                                const float* __restrict__ A,
                                                const float* __restrict__ Wg,
                                                const float* __restrict__ bg,
                                                const float* __restrict__ cmask,
                                                const float* __restrict__ Wa,
                                                const float* __restrict__ ba,
                                                float* __restrict__ compound,
                                                float* __restrict__ hv) {
  __shared__ __align__(16) char pool[65536 + 32768 + 4096 + 640];
  char* reg0 = pool;                                  // xs_lds / hsT_lds
  char* wgp  = pool + 65536;                          // Wg bf16
  float* cred = (float*)(pool + 98304);               // 8 x 128
  float* comp = (float*)(pool + 98304 + 4096);        // 128
  float* scsp = (float*)(pool + 98304 + 4096 + 512);  // 1

  const int b = blockIdx.x;
  const int tid = threadIdx.x, lane = tid & 63, w = tid >> 6;  // 8 waves
  const int lj = lane & 15, g = lane >> 4;
  const int rbase = w * 32;                           // wave owns 32 atom rows

  // ---- init xs registers from emb_fp gather (f32, exact)
  float4v xsacc[2][8];
  {
    int frow[2][4];
    #pragma unroll
    for (int m = 0; m < 2; ++m)
      #pragma unroll
      for (int jj = 0; jj < 4; ++jj)
        frow[m][jj] = fp[b * NA + rbase + m * 16 + g * 4 + jj];
    #pragma unroll
    for (int m = 0; m < 2; ++m)
      #pragma unroll
      for (int c = 0; c < 8; ++c)
        #pragma unroll
        for (int jj = 0; jj < 4; ++jj)
          xsacc[m][c][jj] = emb[(long)frow[m][jj] * DIM + c * 16 + lj];
  }

  #pragma unroll 1
  for (int lp = 0; lp < 3; ++lp) {
    __syncthreads();   // region0 free (prev layer's adj reads done)

    // stage Wg[lp] as bf16 into wgp
    const float* Wgl = Wg + lp * DIM * DIM;
    for (int i = tid; i < 128 * 16; i += 512) {
      int row = i >> 4, c8 = (i & 15) * 8;
      float4 v0 = *(const float4*)&Wgl[row * DIM + c8];
      float4 v1 = *(const float4*)&Wgl[row * DIM + c8 + 4];
      short8v s;
      s[0] = (short)f2bf(v0.x); s[1] = (short)f2bf(v0.y);
      s[2] = (short)f2bf(v0.z); s[3] = (short)f2bf(v0.w);
      s[4] = (short)f2bf(v1.x); s[5] = (short)f2bf(v1.y);
      s[6] = (short)f2bf(v1.z); s[7] = (short)f2bf(v1.w);
      *(short8v*)(wgp + wga(row, c8 * 2)) = s;
    }

    // write xs regs -> xs_lds bf16
    #pragma unroll
    for (int m = 0; m < 2; ++m) {
      #pragma unroll
      for (int jj = 0; jj < 4; ++jj) {
        int r = rbase + m * 16 + g * 4 + jj;
        #pragma unroll
        for (int c = 0; c < 8; ++c)
          *(unsigned short*)(reg0 + xsa(r, (c * 16 + lj) * 2)) =
              f2bf(xsacc[m][c][jj]);
      }
    }
    __syncthreads();

    // hs GEMM: hacc[m][c] = xs @ Wg^T  (wave's own 32 rows)
    float4v hacc[2][8];
    #pragma unroll
    for (int m = 0; m < 2; ++m)
      #pragma unroll
      for (int c = 0; c < 8; ++c) hacc[m][c] = (float4v){0.f, 0.f, 0.f, 0.f};
    #pragma unroll
    for (int ks = 0; ks < 4; ++ks) {
      short8v a0 = *(const short8v*)(reg0 + xsa(rbase + lj,      ks * 64 + g * 16));
      short8v a1 = *(const short8v*)(reg0 + xsa(rbase + 16 + lj, ks * 64 + g * 16));
      #pragma unroll
      for (int c = 0; c < 8; ++c) {
        short8v bf = *(const short8v*)(wgp + wga(c * 16 + lj, ks * 64 + g * 16));
        hacc[0][c] = __builtin_amdgcn_mfma_f32_16x16x32_bf16(a0, bf, hacc[0][c], 0, 0, 0);
        hacc[1][c] = __builtin_amdgcn_mfma_f32_16x16x32_bf16(a1, bf, hacc[1][c], 0, 0, 0);
      }
    }
    __syncthreads();   // all xs_lds reads done before overlay

    // relu(hacc+bg) -> hsT_lds (transposed, overlays region0)
    #pragma unroll
    for (int m = 0; m < 2; ++m) {
      int n0 = rbase + m * 16 + g * 4;
      #pragma unroll
      for (int c = 0; c < 8; ++c) {
        int e = c * 16 + lj;
        float bias = bg[lp * DIM + e];
        short4v s;
        #pragma unroll
        for (int jj = 0; jj < 4; ++jj)
          s[jj] = (short)f2bf(fmaxf(hacc[m][c][jj] + bias, 0.f));
        *(short4v*)(reg0 + hta(e, n0 * 2)) = s;
      }
    }
    __syncthreads();

    // adj GEMM: xsacc += A @ hs   (A from global f32 -> bf16)
    #pragma unroll 1
    for (int ks = 0; ks < 8; ++ks) {
      short8v af[2];
      #pragma unroll
      for (int m = 0; m < 2; ++m) {
        const float* p = &A[((long)b * NA + rbase + m * 16 + lj) * NA + ks * 32 + g * 8];
        float4 x = *(const float4*)p, y = *(const float4*)(p + 4);
        short8v t;
        t[0] = (short)f2bf(x.x); t[1] = (short)f2bf(x.y);
        t[2] = (short)f2bf(x.z); t[3] = (short)f2bf(x.w);
        t[4] = (short)f2bf(y.x); t[5] = (short)f2bf(y.y);
        t[6] = (short)f2bf(y.z); t[7] = (short)f2bf(y.w);
        af[m] = t;
      }
      #pragma unroll
      for (int c = 0; c < 8; ++c) {
        short8v bf = *(const short8v*)(reg0 + hta(c * 16 + lj, ks * 64 + g * 16));
        xsacc[0][c] = __builtin_amdgcn_mfma_f32_16x16x32_bf16(af[0], bf, xsacc[0][c], 0, 0, 0);
        xsacc[1][c] = __builtin_amdgcn_mfma_f32_16x16x32_bf16(af[1], bf, xsacc[1][c], 0, 0, 0);
      }
    }
  }
  __syncthreads();

  // ---- compound mean (masked) from xs registers
  {
    float cm[2][4];
    #pragma unroll
    for (int m = 0; m < 2; ++m)
      #pragma unroll
      for (int jj = 0; jj < 4; ++jj)
        cm[m][jj] = cmask[b * NA + rbase + m * 16 + g * 4 + jj];
    #pragma unroll
    for (int c = 0; c < 8; ++c) {
      float p = 0.f;
      #pragma unroll
      for (int m = 0; m < 2; ++m)
        #pragma unroll
        for (int jj = 0; jj < 4; ++jj)
          p = fmaf(xsacc[m][c][jj], cm[m][jj], p);
      p += __shfl_xor(p, 16);
      p += __shfl_xor(p, 32);
      if (g == 0) cred[w * DIM + c * 16 + lj] = p;
    }
    if (w == 0) {
      float s = 0.f;
      for (int i = lane; i < NA; i += 64) s += cmask[b * NA + i];
      #pragma unroll
      for (int o = 32; o > 0; o >>= 1) s += __shfl_xor(s, o);
      if (lane == 0) scsp[0] = s;
    }
  }
  __syncthreads();
  if (tid < DIM) {
    float s = 0.f;
    #pragma unroll
    for (int ww = 0; ww < 8; ++ww) s += cred[ww * DIM + tid];
    float c = s / scsp[0];
    compound[b * DIM + tid] = c;
    comp[tid] = c;
  }
  __syncthreads();
  if (tid < DIM) {
    float acc = 0.f;
    for (int d = 0; d < DIM; d += 4) {
      float4 wv = *(const float4*)&Wa[tid * DIM + d];
      float4 x  = *(const float4*)&comp[d];
      acc = fmaf(x.x, wv.x, fmaf(x.y, wv.y, fmaf(x.z, wv.z, fmaf(x.w, wv.w, acc))));
    }
    hv[b * DIM + tid] = fmaxf(acc + ba[tid], 0.f);
  }
}

// ------------------------- fp8 conv phase helper (Toeplitz MFMA) ------------
template <int N_RC, bool ROWCHK, bool BF16OUT>
__device__ inline void conv_fp8(const char* __restrict__ src, char* __restrict__ dst,
                                unsigned short* __restrict__ dstX,
                                const long* bfr, float bias, int dstart,
                                int lane, int cc) {
  const int lj = lane & 15, k0 = (lane >> 4) * 8;
  const int acol = 8 + cc * 16 + k0;
  for (int rc = 0; rc < N_RC; ++rc) {
    float4v acc = {0.f, 0.f, 0.f, 0.f};
    #pragma unroll
    for (int ki = 0; ki < KSZ; ++ki) {
      int srow = rc * 16 + lj + ki;
      long a = *(const long*)(src + srow * FRS + acol);
      acc = __builtin_amdgcn_mfma_f32_16x16x32_fp8_fp8(a, bfr[ki], acc, 0, 0, 0);
    }
    int orow = rc * 16 + (lane >> 4) * 4;
    int ocol = cc * 16 + lj;
    #pragma unroll
    for (int jj = 0; jj < 4; ++jj) {
      float v = fmaxf(acc[jj] + bias, 0.f);
      if constexpr (BF16OUT) {
        dstX[(orow + jj) * XRS + ocol] = f2bf(v);
      } else {
        char sv = 0;
        if (!ROWCHK || (unsigned)(dstart + orow + jj) < LPROT) {
          int p = __builtin_amdgcn_cvt_pk_fp8_f32(v, 0.f, 0, false);
          sv = (char)p;
        }
        dst[(orow + jj) * FRS + 8 + ocol] = sv;
      }
    }
  }
}

// ------------------- fused protein branch: gather+conv3(fp8 MFMA)+hs+attn
__global__ __launch_bounds__(512, 6) void k_protein(const int* __restrict__ words,
                                                    const float* __restrict__ emb_word,
                                                    const float* __restrict__ Wc,
                                                    const float* __restrict__ bc,
                                                    const float* __restrict__ Wa,
                                                    const float* __restrict__ ba,
                                                    const float* __restrict__ hvec,
                                                    const float* __restrict__ pmask,
                                                    float* __restrict__ prot_part) {
  __shared__ __align__(16) char pool[50752];
  char* buf0 = pool;                                     // fp8, 106x152 (16128)
  char* buf1 = pool + 16128;                             // fp8, 96x152 (14592)
  unsigned short* bufX = (unsigned short*)(pool + 30720);// bf16 64x136 (17408)
  float* wpad = (float*)(pool + 48128);                  // 11x48 f32 (2112)
  float* h_s  = (float*)(pool + 50240);                  // 128 f32 (512)
  // overlays in buf1 region (dead after conv L2):
  float* wpart = (float*)(pool + 16128);                 // 64x8
  float* w_l   = (float*)(pool + 16128 + 2048);          // 64
  float* red   = (float*)(pool + 16128 + 2304);          // 4x128

  const int tile = blockIdx.x, b = blockIdx.y;
  const int r0   = tile * TROWS;
  const int tid  = threadIdx.x;
  const int lane = tid & 63, wave = tid >> 6;       // 8 waves
  const int lj   = lane & 15;
  const int k0   = (lane >> 4) * 8;
  const int cc   = wave;                            // 16-col chunk per wave

  // ---- zero fp8 buffers
  {
    int4 z = {0, 0, 0, 0};
    int4* p0 = (int4*)pool;
    for (int i = tid; i < 30720 / 16; i += 512) p0[i] = z;
  }
  if (tid < DIM) h_s[tid] = hvec[b * DIM + tid];
  __syncthreads();

  // ---- gather input rows r0-15 .. r0+90 as fp8 into buf0
  for (int idx = tid; idx < B0_ROWS * 32; idx += 512) {
    int rloc = idx >> 5, c4 = idx & 31;
    int rg = r0 - 15 + rloc;
    if (rg >= 0 && rg < LPROT) {
      int w = words[b * LPROT + rg];
      float4 v = ((const float4*)(emb_word + (long)w * DIM))[c4];
      int p = __builtin_amdgcn_cvt_pk_fp8_f32(v.x, v.y, 0, false);
      p = __builtin_amdgcn_cvt_pk_fp8_f32(v.z, v.w, p, true);
      *(int*)(buf0 + rloc * FRS + 8 + c4 * 4) = p;
    }
  }

  const int bbase = 15 + k0 - lj;        // wpad col base

  // ---- 3 conv layers (fp8 Toeplitz MFMA)
  #pragma unroll 1
  for (int lp = 0; lp < 3; ++lp) {
    __syncthreads();
    for (int i = tid; i < KSZ * 48; i += 512) wpad[i] = 0.f;
    __syncthreads();
    if (tid < KSZ * KSZ) wpad[(tid / KSZ) * 48 + 18 + tid % KSZ] = Wc[lp * KSZ * KSZ + tid];
    __syncthreads();

    long bfr[KSZ];
    #pragma unroll
    for (int ki = 0; ki < KSZ; ++ki) {
      const float* wr = wpad + ki * 48 + bbase;
      int lo = __builtin_amdgcn_cvt_pk_fp8_f32(wr[0], wr[1], 0, false);
      lo = __builtin_amdgcn_cvt_pk_fp8_f32(wr[2], wr[3], lo, true);
      int hi = __builtin_amdgcn_cvt_pk_fp8_f32(wr[4], wr[5], 0, false);
      hi = __builtin_amdgcn_cvt_pk_fp8_f32(wr[6], wr[7], hi, true);
      bfr[ki] = ((long)hi << 32) | (unsigned)lo;
    }
    float bias = bc[lp];

    if (lp == 0)
      conv_fp8<6, true, false>(buf0, buf1, nullptr, bfr, bias, r0 - 10, lane, cc);
    else if (lp == 1)
      conv_fp8<5, true, false>(buf1, buf0, nullptr, bfr, bias, r0 - 5, lane, cc);
    else
      conv_fp8<4, false, true>(buf0, nullptr, bufX, bfr, bias, r0, lane, cc);
  }
  __syncthreads();

  // ---- hs = relu(X @ Wa^T + ba): X = bufX (bf16), output written in place
  {
    const char* xb = (const char*)bufX;
    float4v acc[4];
    #pragma unroll
    for (int rc = 0; rc < 4; ++rc) acc[rc] = (float4v){0.f, 0.f, 0.f, 0.f};
    #pragma unroll
    for (int ks = 0; ks < 4; ++ks) {
      const float* wrow = Wa + (cc * 16 + lj) * DIM + ks * 32 + k0;
      float4 wa = *(const float4*)wrow;
      float4 wb = *(const float4*)(wrow + 4);
      short8v bf;
      bf[0] = (short)f2bf(wa.x); bf[1] = (short)f2bf(wa.y);
      bf[2] = (short)f2bf(wa.z); bf[3] = (short)f2bf(wa.w);
      bf[4] = (short)f2bf(wb.x); bf[5] = (short)f2bf(wb.y);
      bf[6] = (short)f2bf(wb.z); bf[7] = (short)f2bf(wb.w);
      #pragma unroll
      for (int rc = 0; rc < 4; ++rc) {
        short8v a = *(const short8v*)(xb + (rc * 16 + lj) * (XRS * 2) + (ks * 32 + k0) * 2);
        acc[rc] = __builtin_amdgcn_mfma_f32_16x16x32_bf16(a, bf, acc[rc], 0, 0, 0);
      }
    }
    __syncthreads();   // all X reads complete before in-place overwrite
    float bav = ba[cc * 16 + lj];
    #pragma unroll
    for (int rc = 0; rc < 4; ++rc) {
      int orow = rc * 16 + (lane >> 4) * 4;
      int ocol = cc * 16 + lj;
      #pragma unroll
      for (int jj = 0; jj < 4; ++jj) {
        float v = fmaxf(acc[rc][jj] + bav, 0.f);
        bufX[(orow + jj) * XRS + ocol] = f2bf(v);
      }
    }
  }
  __syncthreads();

  // ---- attention weights: w_l = tanh(hs[l]·h) * pmask
  {
    int l = tid >> 3, part = tid & 7, d0 = part * 16;
    float s = 0.f;
    #pragma unroll
    for (int dd = 0; dd < 16; ++dd)
      s = fmaf(bf2f(bufX[l * XRS + d0 + dd]), h_s[d0 + dd], s);
    wpart[l * 8 + part] = s;
  }
  __syncthreads();
  if (tid < TROWS) {
    float s = 0.f;
    #pragma unroll
    for (int p = 0; p < 8; ++p) s += wpart[tid * 8 + p];
    w_l[tid] = tanhf(s) * pmask[b * LPROT + r0 + tid];
  }
  __syncthreads();

  // ---- partial protein numerator
  {
    int e = tid & 127, g = tid >> 7;
    float s = 0.f;
    #pragma unroll
    for (int j = 0; j < 16; ++j) {
      int l = g * 16 + j;
      s = fmaf(w_l[l], bf2f(bufX[l * XRS + e]), s);
    }
    red[g * DIM + e] = s;
  }
  __syncthreads();
  if (tid < DIM)
    prot_part[((long)b * NTILES + tile) * DIM + tid] =
        red[tid] + red[DIM + tid] + red[2 * DIM + tid] + red[3 * DIM + tid];
}

// ------------------------------------------------ head MLP + affinity per b
__global__ __launch_bounds__(256) void k_head(const float* __restrict__ prot_part,
                                              const float* __restrict__ pmask,
                                              const float* __restrict__ compound,
                                              const float* __restrict__ Wo,
                                              const float* __restrict__ bo,
                                              const float* __restrict__ Wi,
                                              const float* __restrict__ bi,
                                              float* __restrict__ out) {
  int b = blockIdx.x, tid = threadIdx.x;
  __shared__ float cat[2 * DIM];
  __shared__ float redl[256];

  float ps = 0.f;
  for (int l = tid; l < LPROT; l += 256) ps += pmask[b * LPROT + l];
  redl[tid] = ps; __syncthreads();
  for (int st = 128; st > 0; st >>= 1) {
    if (tid < st) redl[tid] += redl[tid + st];
    __syncthreads();
  }
  float pden = redl[0];
  __syncthreads();

  if (tid < DIM) {
    cat[tid] = compound[b * DIM + tid];
    float s = 0.f;
    for (int t = 0; t < NTILES; ++t) s += prot_part[(b * NTILES + t) * DIM + tid];
    cat[DIM + tid] = s / pden;
  }
  __syncthreads();

  for (int j = 0; j < 2; ++j) {
    const float* W = Wo + j * 2 * DIM * 2 * DIM + tid * 2 * DIM;
    float acc = 0.f;
    for (int d = 0; d < 2 * DIM; d += 4) {
      float4 c = *(const float4*)&cat[d];
      float4 w = *(const float4*)&W[d];
      acc = fmaf(c.x, w.x, fmaf(c.y, w.y, fmaf(c.z, w.z, fmaf(c.w, w.w, acc))));
    }
    float v = fmaxf(acc + bo[j * 2 * DIM + tid], 0.f);
    __syncthreads();
    cat[tid] = v;
    __syncthreads();
  }

  float p = cat[tid] * Wi[tid];
  redl[tid] = p; __syncthreads();
  for (int st = 128; st > 0; st >>= 1) {
    if (tid < st) redl[tid] += redl[tid + st];
    __syncthreads();
  }
  if (tid == 0) out[1 + b] = redl[0] + bi[0];
}

// ----------------------------------------------------------------- MSE loss
__global__ void k_loss(const float* __restrict__ label, float* __restrict__ out) {
  int t = threadIdx.x;
  float d = out[1 + t] - label[t];
  float v = d * d;
  #pragma unroll
  for (int s = 32; s > 0; s >>= 1) v += __shfl_down(v, s);
  if (t == 0) out[0] = v * (1.f / 64.f);
}

extern "C" void kernel_launch(void* const* d_in, const int* in_sizes, int n_in,
                              void* d_out, int out_size, void* d_ws, size_t ws_size,
                              hipStream_t stream) {
  const int*   fingerprints = (const int*)d_in[0];
  const float* adjacency    = (const float*)d_in[1];
  const int*   words        = (const int*)d_in[2];
  const float* cmask        = (const float*)d_in[3];
  const float* pmask        = (const float*)d_in[4];
  const float* label        = (const float*)d_in[5];
  const float* emb_fp       = (const float*)d_in[6];
  const float* emb_word     = (const float*)d_in[7];
  const float* Wg           = (const float*)d_in[8];
  const float* bg           = (const float*)d_in[9];
  const float* Wc           = (const float*)d_in[10];
  const float* bc           = (const float*)d_in[11];
  const float* Wa           = (const float*)d_in[12];
  const float* ba           = (const float*)d_in[13];
  const float* Wo           = (const float*)d_in[14];
  const float* bo           = (const float*)d_in[15];
  const float* Wi           = (const float*)d_in[16];
  const float* bi           = (const float*)d_in[17];
  float* out = (float*)d_out;

  float* ws        = (float*)d_ws;
  float* compound  = ws;                       // 64*128
  float* hv        = compound + NB * DIM;      // 64*128
  float* prot_part = hv + NB * DIM;            // 64*32*128

  k_gnn<<<NB, 512, 0, stream>>>(fingerprints, emb_fp, adjacency, Wg, bg,
                                cmask, Wa, ba, compound, hv);
  k_protein<<<dim3(NTILES, NB), 512, 0, stream>>>(words, emb_word, Wc, bc, Wa, ba,
                                                  hv, pmask, prot_part);
  k_head<<<NB, 256, 0, stream>>>(prot_part, pmask, compound, Wo, bo, Wi, bi, out);
  k_loss<<<1, 64, 0, stream>>>(label, out);
}